// Round 6
// baseline (4630.178 us; speedup 1.0000x reference)
//
#include <hip/hip_runtime.h>
#include <hip/hip_bf16.h>

#define NN 50000
#define NE 800000
#define LDIM 128
#define NSTEPS 10

typedef __hip_bfloat16 bf16;
typedef __bf16 bf8v __attribute__((ext_vector_type(8)));
typedef float f4v __attribute__((ext_vector_type(4)));
typedef unsigned short u16x8 __attribute__((ext_vector_type(8)));

__device__ inline float bflo(unsigned int u) {
    union { unsigned int i; float f; } x; x.i = u << 16; return x.f;
}
__device__ inline float bfhi(unsigned int u) {
    union { unsigned int i; float f; } x; x.i = u & 0xffff0000u; return x.f;
}
__device__ inline unsigned short f2bf(float f) {
    __hip_bfloat16 h = __float2bfloat16(f);
    unsigned short u; __builtin_memcpy(&u, &h, 2); return u;
}

// ---------------- CSR build: histogram, scan, scatter ----------------

__global__ void k_hist(const int* __restrict__ rcv, int* __restrict__ cnt) {
    int i = blockIdx.x * 256 + threadIdx.x;
    if (i < NE) atomicAdd(&cnt[rcv[i]], 1);
}

__global__ __launch_bounds__(1024) void k_scan(
    const int* __restrict__ cnt, int* __restrict__ row_start,
    int* __restrict__ cur, float* __restrict__ degf) {
    __shared__ int part[1024];
    const int t = threadIdx.x;
    const int CH = (NN + 1023) / 1024;  // 49
    int b0 = t * CH, b1 = b0 + CH; if (b1 > NN) b1 = NN; if (b0 > NN) b0 = NN;
    int s = 0;
    for (int i = b0; i < b1; i++) s += cnt[i];
    part[t] = s;
    __syncthreads();
    for (int off = 1; off < 1024; off <<= 1) {
        int v = (t >= off) ? part[t - off] : 0;
        __syncthreads();
        part[t] += v;
        __syncthreads();
    }
    int run = part[t] - s;  // exclusive prefix
    for (int i = b0; i < b1; i++) {
        row_start[i] = run; cur[i] = run; degf[i] = (float)cnt[i];
        run += cnt[i];
    }
    if (t == 1023) row_start[NN] = part[1023];
}

__global__ void k_scatter(const int* __restrict__ rcv, int* __restrict__ cur,
                          int* __restrict__ eidx) {
    int i = blockIdx.x * 256 + threadIdx.x;
    if (i < NE) {
        int p = atomicAdd(&cur[rcv[i]], 1);
        eidx[p] = i;
    }
}

__global__ void k_center(const float* __restrict__ pos, float* __restrict__ csum) {
    __shared__ float s[3][256];
    float a = 0.f, b = 0.f, c = 0.f;
    for (int i = blockIdx.x * 256 + threadIdx.x; i < NN; i += gridDim.x * 256) {
        a += pos[3 * i]; b += pos[3 * i + 1]; c += pos[3 * i + 2];
    }
    int t = threadIdx.x;
    s[0][t] = a; s[1][t] = b; s[2][t] = c;
    __syncthreads();
    for (int off = 128; off > 0; off >>= 1) {
        if (t < off) {
            s[0][t] += s[0][t + off];
            s[1][t] += s[1][t + off];
            s[2][t] += s[2][t + off];
        }
        __syncthreads();
    }
    if (t == 0) {
        atomicAdd(&csum[0], s[0][0]);
        atomicAdd(&csum[1], s[1][0]);
        atomicAdd(&csum[2], s[2][0]);
    }
}

// ---------------- weight prep: fp32 -> bf16 B-frag order; lo=1 emits bf16(x - bf16(x)) ----------------

__global__ void k_prep_w(const float* __restrict__ w, unsigned short* __restrict__ wf,
                         int KT, int Ksrc, int lo) {
    int b = blockIdx.x;
    int s = b / (KT * 8), rem = b % (KT * 8);
    int kt = rem / 8, nt = rem % 8;
    int lane = threadIdx.x, col = lane & 15, quad = lane >> 4;
    const float* W = w + (size_t)s * Ksrc * 128;
    u16x8 o;
#pragma unroll
    for (int jj = 0; jj < 8; jj++) {
        int k = kt * 32 + quad * 8 + jj;
        float x = (k < Ksrc) ? W[(size_t)k * 128 + nt * 16 + col] : 0.f;
        unsigned short h = f2bf(x);
        if (lo) h = f2bf(x - bflo(h));
        o[jj] = h;
    }
    *(u16x8*)(wf + (((size_t)b) * 64 + lane) * 8) = o;
}

// ---------------- standalone CSR aggregation: one wave per node, high occupancy ----------------

__global__ __launch_bounds__(256) void k_agg(
    const unsigned short* __restrict__ el,
    const int* __restrict__ eidx, const int* __restrict__ row_start,
    float* __restrict__ agg) {
    const int wave = threadIdx.x >> 6, lane = threadIdx.x & 63;
    const int n = blockIdx.x * 4 + wave;
    if (n >= NN) return;
    const int sub = lane >> 4, c16 = lane & 15;
    const int st = row_start[n], en = row_start[n + 1];
    float s[8];
#pragma unroll
    for (int k = 0; k < 8; k++) s[k] = 0.f;
    for (int q = st + sub; q < en; q += 4) {
        uint4 v = *(const uint4*)(el + (size_t)eidx[q] * 128 + c16 * 8);
        s[0] += bflo(v.x); s[1] += bfhi(v.x);
        s[2] += bflo(v.y); s[3] += bfhi(v.y);
        s[4] += bflo(v.z); s[5] += bfhi(v.z);
        s[6] += bflo(v.w); s[7] += bfhi(v.w);
    }
#pragma unroll
    for (int k = 0; k < 8; k++) {
        s[k] += __shfl_xor(s[k], 16);
        s[k] += __shfl_xor(s[k], 32);
    }
    if (sub == 0) {
        float4 a = {s[0], s[1], s[2], s[3]}, b = {s[4], s[5], s[6], s[7]};
        *(float4*)(agg + (size_t)n * 128 + c16 * 8) = a;
        *(float4*)(agg + (size_t)n * 128 + c16 * 8 + 4) = b;
    }
}

// ---------------- MFMA node encoder (split-precision): feat(23 pad 32, hi|lo) -> 128 -> 128 ----------------

__global__ __launch_bounds__(256) void k_node_enc_m(
    const float* __restrict__ pos, const float* __restrict__ vel,
    const int* __restrict__ rid, const float* __restrict__ remb,
    const float* __restrict__ degf, const float* __restrict__ csum,
    const unsigned short* __restrict__ w1h, const unsigned short* __restrict__ w1l,
    const float* __restrict__ b1,
    const unsigned short* __restrict__ w2h, const unsigned short* __restrict__ w2l,
    const float* __restrict__ b2,
    float* __restrict__ nl, unsigned short* __restrict__ nlb) {
    __shared__ __align__(16) unsigned short feat_s[32 * 72];   // [hi(32)|lo(32)|pad]
    __shared__ __align__(16) unsigned short hid_s[32 * 264];   // [hi(128)|lo(128)|pad]
    const int tid = threadIdx.x, wave = tid >> 6, lane = tid & 63;
    const int col = lane & 15, quad = lane >> 4;
    bf8v W1H[2], W1L[2], W2H[4][2], W2L[4][2];
#pragma unroll
    for (int t = 0; t < 2; t++) {
        W1H[t] = *(const bf8v*)(w1h + ((size_t)(2 * wave + t) * 64 + lane) * 8);
        W1L[t] = *(const bf8v*)(w1l + ((size_t)(2 * wave + t) * 64 + lane) * 8);
    }
#pragma unroll
    for (int kt = 0; kt < 4; kt++)
#pragma unroll
        for (int t = 0; t < 2; t++) {
            W2H[kt][t] = *(const bf8v*)(w2h + ((size_t)(kt * 8 + 2 * wave + t) * 64 + lane) * 8);
            W2L[kt][t] = *(const bf8v*)(w2l + ((size_t)(kt * 8 + 2 * wave + t) * 64 + lane) * 8);
        }
    float bias1[2], bias2[2];
#pragma unroll
    for (int t = 0; t < 2; t++) {
        bias1[t] = b1[(2 * wave + t) * 16 + col];
        bias2[t] = b2[(2 * wave + t) * 16 + col];
    }
    float cx = csum[0] * (1.0f / NN), cy = csum[1] * (1.0f / NN), cz = csum[2] * (1.0f / NN);
    uint4 z = {0u, 0u, 0u, 0u};
    for (int s2 = tid; s2 < 288; s2 += 256) *(uint4*)(feat_s + s2 * 8) = z;  // zero K-pad

    for (int it = 0; it < 4; it++) {
        const int base = blockIdx.x * 128 + it * 32;
        if (base >= NN) break;
        __syncthreads();
        if (tid < 32) {
            int n = base + tid; if (n > NN - 1) n = NN - 1;
            float v[23];
            v[0] = vel[3 * n]; v[1] = vel[3 * n + 1]; v[2] = vel[3 * n + 2];
            v[3] = pos[3 * n] - cx; v[4] = pos[3 * n + 1] - cy; v[5] = pos[3 * n + 2] - cz;
            v[6] = degf[n];
            int rb = rid[n] * 16;
#pragma unroll
            for (int k = 0; k < 16; k++) v[7 + k] = remb[rb + k];
            unsigned short* f = feat_s + tid * 72;
#pragma unroll
            for (int k = 0; k < 23; k++) {
                unsigned short h = f2bf(v[k]);
                f[k] = h; f[32 + k] = f2bf(v[k] - bflo(h));
            }
        }
        __syncthreads();
        f4v acc[2][2];
#pragma unroll
        for (int mt = 0; mt < 2; mt++)
#pragma unroll
            for (int t = 0; t < 2; t++) acc[mt][t] = (f4v){0.f, 0.f, 0.f, 0.f};
        {
            bf8v a0h = *(const bf8v*)(feat_s + col * 72 + quad * 8);
            bf8v a1h = *(const bf8v*)(feat_s + (16 + col) * 72 + quad * 8);
            bf8v a0l = *(const bf8v*)(feat_s + col * 72 + 32 + quad * 8);
            bf8v a1l = *(const bf8v*)(feat_s + (16 + col) * 72 + 32 + quad * 8);
#pragma unroll
            for (int t = 0; t < 2; t++) {
                acc[0][t] = __builtin_amdgcn_mfma_f32_16x16x32_bf16(a0h, W1H[t], acc[0][t], 0, 0, 0);
                acc[1][t] = __builtin_amdgcn_mfma_f32_16x16x32_bf16(a1h, W1H[t], acc[1][t], 0, 0, 0);
                acc[0][t] = __builtin_amdgcn_mfma_f32_16x16x32_bf16(a0l, W1H[t], acc[0][t], 0, 0, 0);
                acc[1][t] = __builtin_amdgcn_mfma_f32_16x16x32_bf16(a1l, W1H[t], acc[1][t], 0, 0, 0);
                acc[0][t] = __builtin_amdgcn_mfma_f32_16x16x32_bf16(a0h, W1L[t], acc[0][t], 0, 0, 0);
                acc[1][t] = __builtin_amdgcn_mfma_f32_16x16x32_bf16(a1h, W1L[t], acc[1][t], 0, 0, 0);
            }
        }
#pragma unroll
        for (int mt = 0; mt < 2; mt++)
#pragma unroll
            for (int t = 0; t < 2; t++) {
                const int nc = (2 * wave + t) * 16 + col;
#pragma unroll
                for (int r = 0; r < 4; r++) {
                    float h = fmaxf(acc[mt][t][r] + bias1[t], 0.f);
                    unsigned short hh = f2bf(h);
                    hid_s[(mt * 16 + quad * 4 + r) * 264 + nc] = hh;
                    hid_s[(mt * 16 + quad * 4 + r) * 264 + 128 + nc] = f2bf(h - bflo(hh));
                }
            }
        __syncthreads();
#pragma unroll
        for (int mt = 0; mt < 2; mt++)
#pragma unroll
            for (int t = 0; t < 2; t++) acc[mt][t] = (f4v){0.f, 0.f, 0.f, 0.f};
#pragma unroll
        for (int kt = 0; kt < 8; kt++) {
            int w = kt & 3;
            bf8v a0 = *(const bf8v*)(hid_s + col * 264 + kt * 32 + quad * 8);
            bf8v a1 = *(const bf8v*)(hid_s + (16 + col) * 264 + kt * 32 + quad * 8);
#pragma unroll
            for (int t = 0; t < 2; t++) {
                acc[0][t] = __builtin_amdgcn_mfma_f32_16x16x32_bf16(a0, W2H[w][t], acc[0][t], 0, 0, 0);
                acc[1][t] = __builtin_amdgcn_mfma_f32_16x16x32_bf16(a1, W2H[w][t], acc[1][t], 0, 0, 0);
            }
        }
#pragma unroll
        for (int kt = 0; kt < 4; kt++) {
            bf8v a0 = *(const bf8v*)(hid_s + col * 264 + kt * 32 + quad * 8);
            bf8v a1 = *(const bf8v*)(hid_s + (16 + col) * 264 + kt * 32 + quad * 8);
#pragma unroll
            for (int t = 0; t < 2; t++) {
                acc[0][t] = __builtin_amdgcn_mfma_f32_16x16x32_bf16(a0, W2L[kt][t], acc[0][t], 0, 0, 0);
                acc[1][t] = __builtin_amdgcn_mfma_f32_16x16x32_bf16(a1, W2L[kt][t], acc[1][t], 0, 0, 0);
            }
        }
        __syncthreads();
#pragma unroll
        for (int mt = 0; mt < 2; mt++)
#pragma unroll
            for (int t = 0; t < 2; t++) {
                const int nc = (2 * wave + t) * 16 + col;
#pragma unroll
                for (int r = 0; r < 4; r++) {
                    const int row = mt * 16 + quad * 4 + r;
                    float v = acc[mt][t][r] + bias2[t];
                    if (base + row < NN) nl[(size_t)(base + row) * 128 + nc] = v;
                    hid_s[row * 264 + nc] = f2bf(v);
                }
            }
        __syncthreads();
#pragma unroll
        for (int p = 0; p < 2; p++) {
            int s2 = p * 256 + tid, e = s2 >> 4, c16 = s2 & 15;
            if (base + e < NN)
                *(uint4*)(nlb + (size_t)(base + e) * 128 + c16 * 8) =
                    *(const uint4*)(hid_s + e * 264 + c16 * 8);
        }
    }
}

// ---------------- MFMA edge encoder (split-precision): feat(9 pad 32, hi|lo) -> 128 -> 128 ----------------

__global__ __launch_bounds__(256) void k_edge_enc_m(
    const float* __restrict__ pos, const float* __restrict__ vel,
    const int* __restrict__ rid, const int* __restrict__ snd, const int* __restrict__ rcv,
    const unsigned short* __restrict__ w1h, const unsigned short* __restrict__ w1l,
    const float* __restrict__ b1,
    const unsigned short* __restrict__ w2h, const unsigned short* __restrict__ w2l,
    const float* __restrict__ b2,
    unsigned short* __restrict__ el) {
    __shared__ __align__(16) unsigned short feat_s[32 * 72];
    __shared__ __align__(16) unsigned short hid_s[32 * 264];
    const int tid = threadIdx.x, wave = tid >> 6, lane = tid & 63;
    const int col = lane & 15, quad = lane >> 4;
    bf8v W1H[2], W1L[2], W2H[4][2], W2L[4][2];
#pragma unroll
    for (int t = 0; t < 2; t++) {
        W1H[t] = *(const bf8v*)(w1h + ((size_t)(2 * wave + t) * 64 + lane) * 8);
        W1L[t] = *(const bf8v*)(w1l + ((size_t)(2 * wave + t) * 64 + lane) * 8);
    }
#pragma unroll
    for (int kt = 0; kt < 4; kt++)
#pragma unroll
        for (int t = 0; t < 2; t++) {
            W2H[kt][t] = *(const bf8v*)(w2h + ((size_t)(kt * 8 + 2 * wave + t) * 64 + lane) * 8);
            W2L[kt][t] = *(const bf8v*)(w2l + ((size_t)(kt * 8 + 2 * wave + t) * 64 + lane) * 8);
        }
    float bias1[2], bias2[2];
#pragma unroll
    for (int t = 0; t < 2; t++) {
        bias1[t] = b1[(2 * wave + t) * 16 + col];
        bias2[t] = b2[(2 * wave + t) * 16 + col];
    }
    uint4 z = {0u, 0u, 0u, 0u};
    for (int s2 = tid; s2 < 288; s2 += 256) *(uint4*)(feat_s + s2 * 8) = z;

    for (int it = 0; it < 4; it++) {
        const int base = blockIdx.x * 128 + it * 32;
        __syncthreads();
        if (tid < 32) {
            int e = base + tid;
            int s = snd[e], r = rcv[e];
            float v[9];
            v[0] = pos[3 * s] - pos[3 * r]; v[1] = pos[3 * s + 1] - pos[3 * r + 1]; v[2] = pos[3 * s + 2] - pos[3 * r + 2];
            v[3] = vel[3 * s] - vel[3 * r]; v[4] = vel[3 * s + 1] - vel[3 * r + 1]; v[5] = vel[3 * s + 2] - vel[3 * r + 2];
            float sq = v[0] * v[0] + v[1] * v[1] + v[2] * v[2];
            v[6] = sqrtf(sq); v[7] = sq;
            v[8] = (rid[s] == rid[r]) ? 1.f : 0.f;
            unsigned short* f = feat_s + tid * 72;
#pragma unroll
            for (int k = 0; k < 9; k++) {
                unsigned short h = f2bf(v[k]);
                f[k] = h; f[32 + k] = f2bf(v[k] - bflo(h));
            }
        }
        __syncthreads();
        f4v acc[2][2];
#pragma unroll
        for (int mt = 0; mt < 2; mt++)
#pragma unroll
            for (int t = 0; t < 2; t++) acc[mt][t] = (f4v){0.f, 0.f, 0.f, 0.f};
        {
            bf8v a0h = *(const bf8v*)(feat_s + col * 72 + quad * 8);
            bf8v a1h = *(const bf8v*)(feat_s + (16 + col) * 72 + quad * 8);
            bf8v a0l = *(const bf8v*)(feat_s + col * 72 + 32 + quad * 8);
            bf8v a1l = *(const bf8v*)(feat_s + (16 + col) * 72 + 32 + quad * 8);
#pragma unroll
            for (int t = 0; t < 2; t++) {
                acc[0][t] = __builtin_amdgcn_mfma_f32_16x16x32_bf16(a0h, W1H[t], acc[0][t], 0, 0, 0);
                acc[1][t] = __builtin_amdgcn_mfma_f32_16x16x32_bf16(a1h, W1H[t], acc[1][t], 0, 0, 0);
                acc[0][t] = __builtin_amdgcn_mfma_f32_16x16x32_bf16(a0l, W1H[t], acc[0][t], 0, 0, 0);
                acc[1][t] = __builtin_amdgcn_mfma_f32_16x16x32_bf16(a1l, W1H[t], acc[1][t], 0, 0, 0);
                acc[0][t] = __builtin_amdgcn_mfma_f32_16x16x32_bf16(a0h, W1L[t], acc[0][t], 0, 0, 0);
                acc[1][t] = __builtin_amdgcn_mfma_f32_16x16x32_bf16(a1h, W1L[t], acc[1][t], 0, 0, 0);
            }
        }
#pragma unroll
        for (int mt = 0; mt < 2; mt++)
#pragma unroll
            for (int t = 0; t < 2; t++) {
                const int nc = (2 * wave + t) * 16 + col;
#pragma unroll
                for (int r = 0; r < 4; r++) {
                    float h = fmaxf(acc[mt][t][r] + bias1[t], 0.f);
                    unsigned short hh = f2bf(h);
                    hid_s[(mt * 16 + quad * 4 + r) * 264 + nc] = hh;
                    hid_s[(mt * 16 + quad * 4 + r) * 264 + 128 + nc] = f2bf(h - bflo(hh));
                }
            }
        __syncthreads();
#pragma unroll
        for (int mt = 0; mt < 2; mt++)
#pragma unroll
            for (int t = 0; t < 2; t++) acc[mt][t] = (f4v){0.f, 0.f, 0.f, 0.f};
#pragma unroll
        for (int kt = 0; kt < 8; kt++) {
            int w = kt & 3;
            bf8v a0 = *(const bf8v*)(hid_s + col * 264 + kt * 32 + quad * 8);
            bf8v a1 = *(const bf8v*)(hid_s + (16 + col) * 264 + kt * 32 + quad * 8);
#pragma unroll
            for (int t = 0; t < 2; t++) {
                acc[0][t] = __builtin_amdgcn_mfma_f32_16x16x32_bf16(a0, W2H[w][t], acc[0][t], 0, 0, 0);
                acc[1][t] = __builtin_amdgcn_mfma_f32_16x16x32_bf16(a1, W2H[w][t], acc[1][t], 0, 0, 0);
            }
        }
#pragma unroll
        for (int kt = 0; kt < 4; kt++) {
            bf8v a0 = *(const bf8v*)(hid_s + col * 264 + kt * 32 + quad * 8);
            bf8v a1 = *(const bf8v*)(hid_s + (16 + col) * 264 + kt * 32 + quad * 8);
#pragma unroll
            for (int t = 0; t < 2; t++) {
                acc[0][t] = __builtin_amdgcn_mfma_f32_16x16x32_bf16(a0, W2L[kt][t], acc[0][t], 0, 0, 0);
                acc[1][t] = __builtin_amdgcn_mfma_f32_16x16x32_bf16(a1, W2L[kt][t], acc[1][t], 0, 0, 0);
            }
        }
        __syncthreads();
#pragma unroll
        for (int mt = 0; mt < 2; mt++)
#pragma unroll
            for (int t = 0; t < 2; t++) {
                const int nc = (2 * wave + t) * 16 + col;
#pragma unroll
                for (int r = 0; r < 4; r++)
                    hid_s[(mt * 16 + quad * 4 + r) * 264 + nc] = f2bf(acc[mt][t][r] + bias2[t]);
            }
        __syncthreads();
#pragma unroll
        for (int p = 0; p < 2; p++) {
            int s2 = p * 256 + tid, e = s2 >> 4, c16 = s2 & 15;
            *(uint4*)(el + (size_t)(base + e) * 128 + c16 * 8) =
                *(const uint4*)(hid_s + e * 264 + c16 * 8);
        }
    }
}

// ---------------- MFMA edge processor step (unchanged — passing baseline) ----------------

__global__ __launch_bounds__(256) void k_edge_step(
    unsigned short* __restrict__ el, const unsigned short* __restrict__ nlb,
    const int* __restrict__ snd, const int* __restrict__ rcv,
    const unsigned short* __restrict__ w1f, const float* __restrict__ b1,
    const unsigned short* __restrict__ w2f, const float* __restrict__ b2) {
    __shared__ __align__(16) unsigned short inl_s[32 * 392];
    __shared__ __align__(16) unsigned short hid_s[32 * 136];
    __shared__ int s_idx[64];
    const int tid = threadIdx.x;
    const int wave = tid >> 6, lane = tid & 63;
    const int col = lane & 15, quad = lane >> 4;

    bf8v W1[12][2], W2[4][2];
#pragma unroll
    for (int kt = 0; kt < 12; kt++)
#pragma unroll
        for (int t = 0; t < 2; t++)
            W1[kt][t] = *(const bf8v*)(w1f + ((size_t)(kt * 8 + 2 * wave + t) * 64 + lane) * 8);
#pragma unroll
    for (int kt = 0; kt < 4; kt++)
#pragma unroll
        for (int t = 0; t < 2; t++)
            W2[kt][t] = *(const bf8v*)(w2f + ((size_t)(kt * 8 + 2 * wave + t) * 64 + lane) * 8);
    float bias1[2], bias2[2];
#pragma unroll
    for (int t = 0; t < 2; t++) {
        bias1[t] = b1[(2 * wave + t) * 16 + col];
        bias2[t] = b2[(2 * wave + t) * 16 + col];
    }

    for (int it = 0; it < 4; it++) {
        const int base = blockIdx.x * 128 + it * 32;
        if (tid < 64) s_idx[tid] = (tid < 32) ? snd[base + tid] : rcv[base + tid - 32];
        __syncthreads();
#pragma unroll
        for (int p = 0; p < 2; p++) {
            int s = p * 256 + tid, e = s >> 4, c16 = s & 15;
            *(uint4*)(inl_s + e * 392 + c16 * 8) =
                *(const uint4*)(el + (size_t)(base + e) * 128 + c16 * 8);
            *(uint4*)(inl_s + e * 392 + 128 + c16 * 8) =
                *(const uint4*)(nlb + (size_t)s_idx[e] * 128 + c16 * 8);
            *(uint4*)(inl_s + e * 392 + 256 + c16 * 8) =
                *(const uint4*)(nlb + (size_t)s_idx[32 + e] * 128 + c16 * 8);
        }
        __syncthreads();

        f4v acc[2][2];
#pragma unroll
        for (int mt = 0; mt < 2; mt++)
#pragma unroll
            for (int t = 0; t < 2; t++) acc[mt][t] = (f4v){0.f, 0.f, 0.f, 0.f};
#pragma unroll
        for (int kt = 0; kt < 12; kt++) {
            bf8v a0 = *(const bf8v*)(inl_s + col * 392 + kt * 32 + quad * 8);
            bf8v a1 = *(const bf8v*)(inl_s + (16 + col) * 392 + kt * 32 + quad * 8);
            acc[0][0] = __builtin_amdgcn_mfma_f32_16x16x32_bf16(a0, W1[kt][0], acc[0][0], 0, 0, 0);
            acc[0][1] = __builtin_amdgcn_mfma_f32_16x16x32_bf16(a0, W1[kt][1], acc[0][1], 0, 0, 0);
            acc[1][0] = __builtin_amdgcn_mfma_f32_16x16x32_bf16(a1, W1[kt][0], acc[1][0], 0, 0, 0);
            acc[1][1] = __builtin_amdgcn_mfma_f32_16x16x32_bf16(a1, W1[kt][1], acc[1][1], 0, 0, 0);
        }
#pragma unroll
        for (int mt = 0; mt < 2; mt++)
#pragma unroll
            for (int t = 0; t < 2; t++) {
                const int nc = (2 * wave + t) * 16 + col;
#pragma unroll
                for (int r = 0; r < 4; r++) {
                    float v = fmaxf(acc[mt][t][r] + bias1[t], 0.f);
                    hid_s[(mt * 16 + quad * 4 + r) * 136 + nc] = f2bf(v);
                }
            }
        __syncthreads();

#pragma unroll
        for (int mt = 0; mt < 2; mt++)
#pragma unroll
            for (int t = 0; t < 2; t++) acc[mt][t] = (f4v){0.f, 0.f, 0.f, 0.f};
#pragma unroll
        for (int kt = 0; kt < 4; kt++) {
            bf8v a0 = *(const bf8v*)(hid_s + col * 136 + kt * 32 + quad * 8);
            bf8v a1 = *(const bf8v*)(hid_s + (16 + col) * 136 + kt * 32 + quad * 8);
            acc[0][0] = __builtin_amdgcn_mfma_f32_16x16x32_bf16(a0, W2[kt][0], acc[0][0], 0, 0, 0);
            acc[0][1] = __builtin_amdgcn_mfma_f32_16x16x32_bf16(a0, W2[kt][1], acc[0][1], 0, 0, 0);
            acc[1][0] = __builtin_amdgcn_mfma_f32_16x16x32_bf16(a1, W2[kt][0], acc[1][0], 0, 0, 0);
            acc[1][1] = __builtin_amdgcn_mfma_f32_16x16x32_bf16(a1, W2[kt][1], acc[1][1], 0, 0, 0);
        }
        __syncthreads();
#pragma unroll
        for (int mt = 0; mt < 2; mt++)
#pragma unroll
            for (int t = 0; t < 2; t++) {
                const int nc = (2 * wave + t) * 16 + col;
#pragma unroll
                for (int r = 0; r < 4; r++) {
                    const int row = mt * 16 + quad * 4 + r;
                    float v = acc[mt][t][r] + bias2[t] + bflo((unsigned int)inl_s[row * 392 + nc]);
                    hid_s[row * 136 + nc] = f2bf(v);
                }
            }
        __syncthreads();
#pragma unroll
        for (int p = 0; p < 2; p++) {
            int s = p * 256 + tid, e = s >> 4, c16 = s & 15;
            *(uint4*)(el + (size_t)(base + e) * 128 + c16 * 8) =
                *(const uint4*)(hid_s + e * 136 + c16 * 8);
        }
    }
}

// ---------------- shared node-MLP tile (split-precision), called after A staged in LDS ----------------

__device__ __forceinline__ void node_mlp_tile(
    const int base, const int tid, const int wave, const int col, const int quad,
    unsigned short* __restrict__ a_s, unsigned short* __restrict__ hid_s,
    const bf8v (&W1H)[8][2], const bf8v (&W1L)[8][2],
    const bf8v (&W2H)[4][2], const bf8v (&W2L)[4][2],
    const float (&bias1)[2], const float (&bias2)[2],
    float* __restrict__ nl, unsigned short* __restrict__ nlb) {
    f4v acc[2][2];
#pragma unroll
    for (int mt = 0; mt < 2; mt++)
#pragma unroll
        for (int t = 0; t < 2; t++) acc[mt][t] = (f4v){0.f, 0.f, 0.f, 0.f};
#pragma unroll
    for (int kt = 0; kt < 16; kt++) {
        int w = (kt & 3) + ((kt >> 3) << 2);  // hi/lo halves share W1H frags
        bf8v a0 = *(const bf8v*)(a_s + col * 520 + kt * 32 + quad * 8);
        bf8v a1 = *(const bf8v*)(a_s + (16 + col) * 520 + kt * 32 + quad * 8);
#pragma unroll
        for (int t = 0; t < 2; t++) {
            acc[0][t] = __builtin_amdgcn_mfma_f32_16x16x32_bf16(a0, W1H[w][t], acc[0][t], 0, 0, 0);
            acc[1][t] = __builtin_amdgcn_mfma_f32_16x16x32_bf16(a1, W1H[w][t], acc[1][t], 0, 0, 0);
        }
    }
#pragma unroll
    for (int kt = 0; kt < 8; kt++) {  // W1L on hi segments (nl_hi: kt 0..3, agg_hi: kt 8..11)
        int ka = (kt < 4) ? kt : kt + 4;
        bf8v a0 = *(const bf8v*)(a_s + col * 520 + ka * 32 + quad * 8);
        bf8v a1 = *(const bf8v*)(a_s + (16 + col) * 520 + ka * 32 + quad * 8);
#pragma unroll
        for (int t = 0; t < 2; t++) {
            acc[0][t] = __builtin_amdgcn_mfma_f32_16x16x32_bf16(a0, W1L[kt][t], acc[0][t], 0, 0, 0);
            acc[1][t] = __builtin_amdgcn_mfma_f32_16x16x32_bf16(a1, W1L[kt][t], acc[1][t], 0, 0, 0);
        }
    }
#pragma unroll
    for (int mt = 0; mt < 2; mt++)
#pragma unroll
        for (int t = 0; t < 2; t++) {
            const int nc = (2 * wave + t) * 16 + col;
#pragma unroll
            for (int r = 0; r < 4; r++) {
                float h = fmaxf(acc[mt][t][r] + bias1[t], 0.f);
                unsigned short hh = f2bf(h);
                hid_s[(mt * 16 + quad * 4 + r) * 264 + nc] = hh;
                hid_s[(mt * 16 + quad * 4 + r) * 264 + 128 + nc] = f2bf(h - bflo(hh));
            }
        }
    __syncthreads();
#pragma unroll
    for (int mt = 0; mt < 2; mt++)
#pragma unroll
        for (int t = 0; t < 2; t++) acc[mt][t] = (f4v){0.f, 0.f, 0.f, 0.f};
#pragma unroll
    for (int kt = 0; kt < 8; kt++) {
        int w = kt & 3;
        bf8v a0 = *(const bf8v*)(hid_s + col * 264 + kt * 32 + quad * 8);
        bf8v a1 = *(const bf8v*)(hid_s + (16 + col) * 264 + kt * 32 + quad * 8);
#pragma unroll
        for (int t = 0; t < 2; t++) {
            acc[0][t] = __builtin_amdgcn_mfma_f32_16x16x32_bf16(a0, W2H[w][t], acc[0][t], 0, 0, 0);
            acc[1][t] = __builtin_amdgcn_mfma_f32_16x16x32_bf16(a1, W2H[w][t], acc[1][t], 0, 0, 0);
        }
    }
#pragma unroll
    for (int kt = 0; kt < 4; kt++) {
        bf8v a0 = *(const bf8v*)(hid_s + col * 264 + kt * 32 + quad * 8);
        bf8v a1 = *(const bf8v*)(hid_s + (16 + col) * 264 + kt * 32 + quad * 8);
#pragma unroll
        for (int t = 0; t < 2; t++) {
            acc[0][t] = __builtin_amdgcn_mfma_f32_16x16x32_bf16(a0, W2L[kt][t], acc[0][t], 0, 0, 0);
            acc[1][t] = __builtin_amdgcn_mfma_f32_16x16x32_bf16(a1, W2L[kt][t], acc[1][t], 0, 0, 0);
        }
    }
    __syncthreads();
#pragma unroll
    for (int mt = 0; mt < 2; mt++)
#pragma unroll
        for (int t = 0; t < 2; t++) {
            const int nc = (2 * wave + t) * 16 + col;
#pragma unroll
            for (int r = 0; r < 4; r++) {
                const int row = mt * 16 + quad * 4 + r;
                int n = base + row, ncl = (n < NN) ? n : NN - 1;
                float v = acc[mt][t][r] + bias2[t] + nl[(size_t)ncl * 128 + nc];
                if (n < NN) nl[(size_t)n * 128 + nc] = v;
                hid_s[row * 264 + nc] = f2bf(v);
            }
        }
    __syncthreads();
#pragma unroll
    for (int p = 0; p < 2; p++) {
        int s2 = p * 256 + tid, e = s2 >> 4, cc = s2 & 15;
        if (base + e < NN)
            *(uint4*)(nlb + (size_t)(base + e) * 128 + cc * 8) =
                *(const uint4*)(hid_s + e * 264 + cc * 8);
    }
}

// Primary: agg precomputed (fp32, coalesced). 64 nodes/block (2 tiles), grid 782.
__global__ __launch_bounds__(256) void k_node_step_s(
    float* __restrict__ nl, unsigned short* __restrict__ nlb,
    const float* __restrict__ agg,
    const unsigned short* __restrict__ w1h, const unsigned short* __restrict__ w1l,
    const float* __restrict__ b1,
    const unsigned short* __restrict__ w2h, const unsigned short* __restrict__ w2l,
    const float* __restrict__ b2) {
    __shared__ __align__(16) unsigned short a_s[32 * 520];
    __shared__ __align__(16) unsigned short hid_s[32 * 264];
    const int tid = threadIdx.x, wave = tid >> 6, lane = tid & 63;
    const int col = lane & 15, quad = lane >> 4;
    bf8v W1H[8][2], W1L[8][2], W2H[4][2], W2L[4][2];
#pragma unroll
    for (int kt = 0; kt < 8; kt++)
#pragma unroll
        for (int t = 0; t < 2; t++) {
            W1H[kt][t] = *(const bf8v*)(w1h + ((size_t)(kt * 8 + 2 * wave + t) * 64 + lane) * 8);
            W1L[kt][t] = *(const bf8v*)(w1l + ((size_t)(kt * 8 + 2 * wave + t) * 64 + lane) * 8);
        }
#pragma unroll
    for (int kt = 0; kt < 4; kt++)
#pragma unroll
        for (int t = 0; t < 2; t++) {
            W2H[kt][t] = *(const bf8v*)(w2h + ((size_t)(kt * 8 + 2 * wave + t) * 64 + lane) * 8);
            W2L[kt][t] = *(const bf8v*)(w2l + ((size_t)(kt * 8 + 2 * wave + t) * 64 + lane) * 8);
        }
    float bias1[2], bias2[2];
#pragma unroll
    for (int t = 0; t < 2; t++) {
        bias1[t] = b1[(2 * wave + t) * 16 + col];
        bias2[t] = b2[(2 * wave + t) * 16 + col];
    }
    for (int it = 0; it < 2; it++) {
        const int base = blockIdx.x * 64 + it * 32;
        if (base >= NN) break;
        __syncthreads();
#pragma unroll
        for (int p = 0; p < 4; p++) {
            int s2 = p * 256 + tid, e = s2 >> 5, c4 = s2 & 31;
            int n = base + e; if (n > NN - 1) n = NN - 1;
            float4 v = *(const float4*)(nl + (size_t)n * 128 + c4 * 4);
            float4 g = *(const float4*)(agg + (size_t)n * 128 + c4 * 4);
            ushort4 hi, lo, gh, gl;
            hi.x = f2bf(v.x); lo.x = f2bf(v.x - bflo(hi.x));
            hi.y = f2bf(v.y); lo.y = f2bf(v.y - bflo(hi.y));
            hi.z = f2bf(v.z); lo.z = f2bf(v.z - bflo(hi.z));
            hi.w = f2bf(v.w); lo.w = f2bf(v.w - bflo(hi.w));
            gh.x = f2bf(g.x); gl.x = f2bf(g.x - bflo(gh.x));
            gh.y = f2bf(g.y); gl.y = f2bf(g.y - bflo(gh.y));
            gh.z = f2bf(g.z); gl.z = f2bf(g.z - bflo(gh.z));
            gh.w = f2bf(g.w); gl.w = f2bf(g.w - bflo(gh.w));
            *(ushort4*)(a_s + e * 520 + c4 * 4) = hi;
            *(ushort4*)(a_s + e * 520 + 128 + c4 * 4) = lo;
            *(ushort4*)(a_s + e * 520 + 256 + c4 * 4) = gh;
            *(ushort4*)(a_s + e * 520 + 384 + c4 * 4) = gl;
        }
        __syncthreads();
        node_mlp_tile(base, tid, wave, col, quad, a_s, hid_s,
                      W1H, W1L, W2H, W2L, bias1, bias2, nl, nlb);
    }
}

// Fallback (ws too small for agg buffer): fused CSR gather. 128 nodes/block, grid 391.
__global__ __launch_bounds__(256) void k_node_step_m(
    float* __restrict__ nl, unsigned short* __restrict__ nlb,
    const unsigned short* __restrict__ el,
    const int* __restrict__ eidx, const int* __restrict__ row_start,
    const unsigned short* __restrict__ w1h, const unsigned short* __restrict__ w1l,
    const float* __restrict__ b1,
    const unsigned short* __restrict__ w2h, const unsigned short* __restrict__ w2l,
    const float* __restrict__ b2) {
    __shared__ __align__(16) unsigned short a_s[32 * 520];
    __shared__ __align__(16) unsigned short hid_s[32 * 264];
    const int tid = threadIdx.x, wave = tid >> 6, lane = tid & 63;
    const int col = lane & 15, quad = lane >> 4;
    const int sub = lane >> 4, c16g = lane & 15;
    bf8v W1H[8][2], W1L[8][2], W2H[4][2], W2L[4][2];
#pragma unroll
    for (int kt = 0; kt < 8; kt++)
#pragma unroll
        for (int t = 0; t < 2; t++) {
            W1H[kt][t] = *(const bf8v*)(w1h + ((size_t)(kt * 8 + 2 * wave + t) * 64 + lane) * 8);
            W1L[kt][t] = *(const bf8v*)(w1l + ((size_t)(kt * 8 + 2 * wave + t) * 64 + lane) * 8);
        }
#pragma unroll
    for (int kt = 0; kt < 4; kt++)
#pragma unroll
        for (int t = 0; t < 2; t++) {
            W2H[kt][t] = *(const bf8v*)(w2h + ((size_t)(kt * 8 + 2 * wave + t) * 64 + lane) * 8);
            W2L[kt][t] = *(const bf8v*)(w2l + ((size_t)(kt * 8 + 2 * wave + t) * 64 + lane) * 8);
        }
    float bias1[2], bias2[2];
#pragma unroll
    for (int t = 0; t < 2; t++) {
        bias1[t] = b1[(2 * wave + t) * 16 + col];
        bias2[t] = b2[(2 * wave + t) * 16 + col];
    }
    for (int it = 0; it < 4; it++) {
        const int base = blockIdx.x * 128 + it * 32;
        if (base >= NN) break;
        __syncthreads();
#pragma unroll
        for (int p = 0; p < 4; p++) {
            int s2 = p * 256 + tid, e = s2 >> 5, c4 = s2 & 31;
            int n = base + e; if (n > NN - 1) n = NN - 1;
            float4 v = *(const float4*)(nl + (size_t)n * 128 + c4 * 4);
            ushort4 hi, lo;
            hi.x = f2bf(v.x); lo.x = f2bf(v.x - bflo(hi.x));
            hi.y = f2bf(v.y); lo.y = f2bf(v.y - bflo(hi.y));
            hi.z = f2bf(v.z); lo.z = f2bf(v.z - bflo(hi.z));
            hi.w = f2bf(v.w); lo.w = f2bf(v.w - bflo(hi.w));
            *(ushort4*)(a_s + e * 520 + c4 * 4) = hi;
            *(ushort4*)(a_s + e * 520 + 128 + c4 * 4) = lo;
        }
        for (int i = 0; i < 8; i++) {
            int e = wave * 8 + i, n = base + e;
            if (n < NN) {
                int st = row_start[n], en = row_start[n + 1];
                float s[8];
#pragma unroll
                for (int k = 0; k < 8; k++) s[k] = 0.f;
                for (int q = st + sub; q < en; q += 4) {
                    uint4 v = *(const uint4*)(el + (size_t)eidx[q] * 128 + c16g * 8);
                    s[0] += bflo(v.x); s[1] += bfhi(v.x);
                    s[2] += bflo(v.y); s[3] += bfhi(v.y);
                    s[4] += bflo(v.z); s[5] += bfhi(v.z);
                    s[6] += bflo(v.w); s[7] += bfhi(v.w);
                }
#pragma unroll
                for (int k = 0; k < 8; k++) {
                    s[k] += __shfl_xor(s[k], 16);
                    s[k] += __shfl_xor(s[k], 32);
                }
                if (sub == 0) {
                    u16x8 h8, l8;
#pragma unroll
                    for (int k = 0; k < 8; k++) {
                        h8[k] = f2bf(s[k]);
                        l8[k] = f2bf(s[k] - bflo((unsigned int)h8[k]));
                    }
                    *(u16x8*)(a_s + e * 520 + 256 + c16g * 8) = h8;
                    *(u16x8*)(a_s + e * 520 + 384 + c16g * 8) = l8;
                }
            }
        }
        __syncthreads();
        node_mlp_tile(base, tid, wave, col, quad, a_s, hid_s,
                      W1H, W1L, W2H, W2L, bias1, bias2, nl, nlb);
    }
}

// ---------------- decoder: 128 -> 128 -> 3 (fp32 VALU, reads fp32 nl) ----------------

__global__ __launch_bounds__(128) void k_decode(
    const float* __restrict__ nl,
    const float* __restrict__ w1, const float* __restrict__ b1,
    const float* __restrict__ w2, const float* __restrict__ b2,
    float* __restrict__ out) {
    __shared__ float inl[16][128];
    __shared__ float hid[16][128];
    int j = threadIdx.x;
    int base = blockIdx.x * 16;
    for (int e = 0; e < 16; e++) inl[e][j] = nl[(size_t)(base + e) * 128 + j];
    __syncthreads();
    float acc[16];
#pragma unroll
    for (int e = 0; e < 16; e++) acc[e] = b1[j];
    for (int kc = 0; kc < 16; kc++) {
        float w[8];
#pragma unroll
        for (int t = 0; t < 8; t++) w[t] = w1[(kc * 8 + t) * 128 + j];
#pragma unroll
        for (int e = 0; e < 16; e++) {
            float4 h0 = *(const float4*)&inl[e][kc * 8];
            float4 h1 = *(const float4*)&inl[e][kc * 8 + 4];
            acc[e] = fmaf(h0.x, w[0], acc[e]); acc[e] = fmaf(h0.y, w[1], acc[e]);
            acc[e] = fmaf(h0.z, w[2], acc[e]); acc[e] = fmaf(h0.w, w[3], acc[e]);
            acc[e] = fmaf(h1.x, w[4], acc[e]); acc[e] = fmaf(h1.y, w[5], acc[e]);
            acc[e] = fmaf(h1.z, w[6], acc[e]); acc[e] = fmaf(h1.w, w[7], acc[e]);
        }
    }
#pragma unroll
    for (int e = 0; e < 16; e++) hid[e][j] = fmaxf(acc[e], 0.f);
    __syncthreads();
    if (j < 48) {
        int e = j / 3, ch = j - 3 * (j / 3);
        float s = b2[ch];
        for (int k = 0; k < 128; k++) s = fmaf(hid[e][k], w2[k * 3 + ch], s);
        out[(size_t)(base + e) * 3 + ch] = s;
    }
}

// ---------------- launch ----------------

extern "C" void kernel_launch(void* const* d_in, const int* in_sizes, int n_in,
                              void* d_out, int out_size, void* d_ws, size_t ws_size,
                              hipStream_t stream) {
    (void)in_sizes; (void)n_in; (void)out_size;
    const float* pos   = (const float*)d_in[0];
    const float* vel   = (const float*)d_in[1];
    const int*   rid   = (const int*)d_in[2];
    const int*   snd   = (const int*)d_in[3];
    const int*   rcv   = (const int*)d_in[4];
    const float* remb  = (const float*)d_in[5];
    const float* ne_w1 = (const float*)d_in[6];
    const float* ne_b1 = (const float*)d_in[7];
    const float* ne_w2 = (const float*)d_in[8];
    const float* ne_b2 = (const float*)d_in[9];
    const float* ee_w1 = (const float*)d_in[10];
    const float* ee_b1 = (const float*)d_in[11];
    const float* ee_w2 = (const float*)d_in[12];
    const float* ee_b2 = (const float*)d_in[13];
    const float* pe_w1 = (const float*)d_in[14];
    const float* pe_b1 = (const float*)d_in[15];
    const float* pe_w2 = (const float*)d_in[16];
    const float* pe_b2 = (const float*)d_in[17];
    const float* pn_w1 = (const float*)d_in[18];
    const float* pn_b1 = (const float*)d_in[19];
    const float* pn_w2 = (const float*)d_in[20];
    const float* pn_b2 = (const float*)d_in[21];
    const float* de_w1 = (const float*)d_in[22];
    const float* de_b1 = (const float*)d_in[23];
    const float* de_w2 = (const float*)d_in[24];
    const float* de_b2 = (const float*)d_in[25];
    float* out = (float*)d_out;

    char* p = (char*)d_ws;
    auto carve = [&](size_t bytes) { void* q = (void*)p; p += (bytes + 15) & ~(size_t)15; return q; };
    unsigned short* el    = (unsigned short*)carve((size_t)NE * LDIM * 2);   // 204.8 MB
    float*          nl    = (float*)carve((size_t)NN * LDIM * 4);            // 25.6 MB
    unsigned short* nlb   = (unsigned short*)carve((size_t)NN * LDIM * 2);   // 12.8 MB
    unsigned short* w1f_e = (unsigned short*)carve((size_t)NSTEPS * 12 * 8 * 512 * 2);
    unsigned short* w2f_e = (unsigned short*)carve((size_t)NSTEPS * 4 * 8 * 512 * 2);
    unsigned short* w1h_n = (unsigned short*)carve((size_t)NSTEPS * 8 * 8 * 512 * 2);
    unsigned short* w1l_n = (unsigned short*)carve((size_t)NSTEPS * 8 * 8 * 512 * 2);
    unsigned short* w2h_n = (unsigned short*)carve((size_t)NSTEPS * 4 * 8 * 512 * 2);
    unsigned short* w2l_n = (unsigned short*)carve((size_t)NSTEPS * 4 * 8 * 512 * 2);
    unsigned short* eew1h = (unsigned short*)carve((size_t)1 * 8 * 512 * 2);
    unsigned short* eew1l = (unsigned short*)carve((size_t)1 * 8 * 512 * 2);
    unsigned short* eew2h = (unsigned short*)carve((size_t)4 * 8 * 512 * 2);
    unsigned short* eew2l = (unsigned short*)carve((size_t)4 * 8 * 512 * 2);
    unsigned short* new1h = (unsigned short*)carve((size_t)1 * 8 * 512 * 2);
    unsigned short* new1l = (unsigned short*)carve((size_t)1 * 8 * 512 * 2);
    unsigned short* new2h = (unsigned short*)carve((size_t)4 * 8 * 512 * 2);
    unsigned short* new2l = (unsigned short*)carve((size_t)4 * 8 * 512 * 2);
    int*            eidx  = (int*)carve((size_t)NE * 4);                     // 3.2 MB
    int*            rs    = (int*)carve((size_t)(NN + 1) * 4);
    int*            cnt   = (int*)carve((size_t)NN * 4);
    int*            cur   = (int*)carve((size_t)NN * 4);
    float*          degf  = (float*)carve((size_t)NN * 4);
    float*          csum  = (float*)carve(16);
    // optional agg buffer (25.6 MB) — decision is a pure function of ws_size (graph-safe)
    size_t used = (size_t)(p - (char*)d_ws);
    size_t agg_bytes = (size_t)NN * LDIM * 4;
    bool use_split = (used + agg_bytes) <= ws_size;
    float* agg = use_split ? (float*)carve(agg_bytes) : nullptr;

    hipMemsetAsync(cnt, 0, (size_t)NN * 4, stream);
    hipMemsetAsync(csum, 0, 16, stream);
    k_hist<<<NE / 256, 256, 0, stream>>>(rcv, cnt);
    k_scan<<<1, 1024, 0, stream>>>(cnt, rs, cur, degf);
    k_center<<<64, 256, 0, stream>>>(pos, csum);
    k_scatter<<<NE / 256, 256, 0, stream>>>(rcv, cur, eidx);
    k_prep_w<<<NSTEPS * 12 * 8, 64, 0, stream>>>(pe_w1, w1f_e, 12, 384, 0);
    k_prep_w<<<NSTEPS * 4 * 8, 64, 0, stream>>>(pe_w2, w2f_e, 4, 128, 0);
    k_prep_w<<<NSTEPS * 8 * 8, 64, 0, stream>>>(pn_w1, w1h_n, 8, 256, 0);
    k_prep_w<<<NSTEPS * 8 * 8, 64, 0, stream>>>(pn_w1, w1l_n, 8, 256, 1);
    k_prep_w<<<NSTEPS * 4 * 8, 64, 0, stream>>>(pn_w2, w2h_n, 4, 128, 0);
    k_prep_w<<<NSTEPS * 4 * 8, 64, 0, stream>>>(pn_w2, w2l_n, 4, 128, 1);
    k_prep_w<<<8, 64, 0, stream>>>(ee_w1, eew1h, 1, 9, 0);
    k_prep_w<<<8, 64, 0, stream>>>(ee_w1, eew1l, 1, 9, 1);
    k_prep_w<<<4 * 8, 64, 0, stream>>>(ee_w2, eew2h, 4, 128, 0);
    k_prep_w<<<4 * 8, 64, 0, stream>>>(ee_w2, eew2l, 4, 128, 1);
    k_prep_w<<<8, 64, 0, stream>>>(ne_w1, new1h, 1, 23, 0);
    k_prep_w<<<8, 64, 0, stream>>>(ne_w1, new1l, 1, 23, 1);
    k_prep_w<<<4 * 8, 64, 0, stream>>>(ne_w2, new2h, 4, 128, 0);
    k_prep_w<<<4 * 8, 64, 0, stream>>>(ne_w2, new2l, 4, 128, 1);

    k_node_enc_m<<<(NN + 127) / 128, 256, 0, stream>>>(pos, vel, rid, remb, degf, csum,
                                                       new1h, new1l, ne_b1, new2h, new2l, ne_b2, nl, nlb);
    k_edge_enc_m<<<NE / 128, 256, 0, stream>>>(pos, vel, rid, snd, rcv,
                                               eew1h, eew1l, ee_b1, eew2h, eew2l, ee_b2, el);
    for (int i = 0; i < NSTEPS; i++) {
        k_edge_step<<<NE / 128, 256, 0, stream>>>(el, nlb, snd, rcv,
            w1f_e + (size_t)i * 12 * 8 * 512, pe_b1 + i * 128,
            w2f_e + (size_t)i * 4 * 8 * 512, pe_b2 + i * 128);
        if (use_split) {
            k_agg<<<(NN + 3) / 4, 256, 0, stream>>>(el, eidx, rs, agg);
            k_node_step_s<<<(NN + 63) / 64, 256, 0, stream>>>(nl, nlb, agg,
                w1h_n + (size_t)i * 8 * 8 * 512, w1l_n + (size_t)i * 8 * 8 * 512, pn_b1 + i * 128,
                w2h_n + (size_t)i * 4 * 8 * 512, w2l_n + (size_t)i * 4 * 8 * 512, pn_b2 + i * 128);
        } else {
            k_node_step_m<<<(NN + 127) / 128, 256, 0, stream>>>(nl, nlb, el, eidx, rs,
                w1h_n + (size_t)i * 8 * 8 * 512, w1l_n + (size_t)i * 8 * 8 * 512, pn_b1 + i * 128,
                w2h_n + (size_t)i * 4 * 8 * 512, w2l_n + (size_t)i * 4 * 8 * 512, pn_b2 + i * 128);
        }
    }
    k_decode<<<NN / 16, 128, 0, stream>>>(nl, de_w1, de_b1, de_w2, de_b2, out);
}

// Round 7
// 3839.129 us; speedup vs baseline: 1.2060x; 1.2060x over previous
//
#include <hip/hip_runtime.h>
#include <hip/hip_bf16.h>

#define NN 50000
#define NE 800000
#define LDIM 128
#define NSTEPS 10

typedef __hip_bfloat16 bf16;
typedef __bf16 bf8v __attribute__((ext_vector_type(8)));
typedef float f4v __attribute__((ext_vector_type(4)));
typedef unsigned short u16x8 __attribute__((ext_vector_type(8)));

__device__ inline float bflo(unsigned int u) {
    union { unsigned int i; float f; } x; x.i = u << 16; return x.f;
}
__device__ inline float bfhi(unsigned int u) {
    union { unsigned int i; float f; } x; x.i = u & 0xffff0000u; return x.f;
}
__device__ inline unsigned short f2bf(float f) {
    __hip_bfloat16 h = __float2bfloat16(f);
    unsigned short u; __builtin_memcpy(&u, &h, 2); return u;
}

// ---------------- CSR build: histogram, scan, scatter (writes permuted endpoint arrays) ----------------

__global__ void k_hist(const int* __restrict__ rcv, int* __restrict__ cnt) {
    int i = blockIdx.x * 256 + threadIdx.x;
    if (i < NE) atomicAdd(&cnt[rcv[i]], 1);
}

__global__ __launch_bounds__(1024) void k_scan(
    const int* __restrict__ cnt, int* __restrict__ row_start,
    int* __restrict__ cur, float* __restrict__ degf) {
    __shared__ int part[1024];
    const int t = threadIdx.x;
    const int CH = (NN + 1023) / 1024;  // 49
    int b0 = t * CH, b1 = b0 + CH; if (b1 > NN) b1 = NN; if (b0 > NN) b0 = NN;
    int s = 0;
    for (int i = b0; i < b1; i++) s += cnt[i];
    part[t] = s;
    __syncthreads();
    for (int off = 1; off < 1024; off <<= 1) {
        int v = (t >= off) ? part[t - off] : 0;
        __syncthreads();
        part[t] += v;
        __syncthreads();
    }
    int run = part[t] - s;  // exclusive prefix
    for (int i = b0; i < b1; i++) {
        row_start[i] = run; cur[i] = run; degf[i] = (float)cnt[i];
        run += cnt[i];
    }
    if (t == 1023) row_start[NN] = part[1023];
}

// el lives permanently in CSR (receiver-sorted) order; edge p's endpoints are snd_p[p]/rcv_p[p].
__global__ void k_scatter(const int* __restrict__ snd, const int* __restrict__ rcv,
                          int* __restrict__ cur,
                          int* __restrict__ snd_p, int* __restrict__ rcv_p) {
    int i = blockIdx.x * 256 + threadIdx.x;
    if (i < NE) {
        int r = rcv[i];
        int p = atomicAdd(&cur[r], 1);
        snd_p[p] = snd[i];
        rcv_p[p] = r;
    }
}

__global__ void k_center(const float* __restrict__ pos, float* __restrict__ csum) {
    __shared__ float s[3][256];
    float a = 0.f, b = 0.f, c = 0.f;
    for (int i = blockIdx.x * 256 + threadIdx.x; i < NN; i += gridDim.x * 256) {
        a += pos[3 * i]; b += pos[3 * i + 1]; c += pos[3 * i + 2];
    }
    int t = threadIdx.x;
    s[0][t] = a; s[1][t] = b; s[2][t] = c;
    __syncthreads();
    for (int off = 128; off > 0; off >>= 1) {
        if (t < off) {
            s[0][t] += s[0][t + off];
            s[1][t] += s[1][t + off];
            s[2][t] += s[2][t + off];
        }
        __syncthreads();
    }
    if (t == 0) {
        atomicAdd(&csum[0], s[0][0]);
        atomicAdd(&csum[1], s[1][0]);
        atomicAdd(&csum[2], s[2][0]);
    }
}

// ---------------- weight prep: fp32 -> bf16 B-frag order; lo=1 emits bf16(x - bf16(x)) ----------------

__global__ void k_prep_w(const float* __restrict__ w, unsigned short* __restrict__ wf,
                         int KT, int Ksrc, int lo) {
    int b = blockIdx.x;
    int s = b / (KT * 8), rem = b % (KT * 8);
    int kt = rem / 8, nt = rem % 8;
    int lane = threadIdx.x, col = lane & 15, quad = lane >> 4;
    const float* W = w + (size_t)s * Ksrc * 128;
    u16x8 o;
#pragma unroll
    for (int jj = 0; jj < 8; jj++) {
        int k = kt * 32 + quad * 8 + jj;
        float x = (k < Ksrc) ? W[(size_t)k * 128 + nt * 16 + col] : 0.f;
        unsigned short h = f2bf(x);
        if (lo) h = f2bf(x - bflo(h));
        o[jj] = h;
    }
    *(u16x8*)(wf + (((size_t)b) * 64 + lane) * 8) = o;
}

// ---------------- MFMA node encoder (split-precision): feat(23 pad 32, hi|lo) -> 128 -> 128 ----------------

__global__ __launch_bounds__(256) void k_node_enc_m(
    const float* __restrict__ pos, const float* __restrict__ vel,
    const int* __restrict__ rid, const float* __restrict__ remb,
    const float* __restrict__ degf, const float* __restrict__ csum,
    const unsigned short* __restrict__ w1h, const unsigned short* __restrict__ w1l,
    const float* __restrict__ b1,
    const unsigned short* __restrict__ w2h, const unsigned short* __restrict__ w2l,
    const float* __restrict__ b2,
    float* __restrict__ nl, unsigned short* __restrict__ nlb) {
    __shared__ __align__(16) unsigned short feat_s[32 * 72];   // [hi(32)|lo(32)|pad]
    __shared__ __align__(16) unsigned short hid_s[32 * 264];   // [hi(128)|lo(128)|pad]
    const int tid = threadIdx.x, wave = tid >> 6, lane = tid & 63;
    const int col = lane & 15, quad = lane >> 4;
    bf8v W1H[2], W1L[2], W2H[4][2], W2L[4][2];
#pragma unroll
    for (int t = 0; t < 2; t++) {
        W1H[t] = *(const bf8v*)(w1h + ((size_t)(2 * wave + t) * 64 + lane) * 8);
        W1L[t] = *(const bf8v*)(w1l + ((size_t)(2 * wave + t) * 64 + lane) * 8);
    }
#pragma unroll
    for (int kt = 0; kt < 4; kt++)
#pragma unroll
        for (int t = 0; t < 2; t++) {
            W2H[kt][t] = *(const bf8v*)(w2h + ((size_t)(kt * 8 + 2 * wave + t) * 64 + lane) * 8);
            W2L[kt][t] = *(const bf8v*)(w2l + ((size_t)(kt * 8 + 2 * wave + t) * 64 + lane) * 8);
        }
    float bias1[2], bias2[2];
#pragma unroll
    for (int t = 0; t < 2; t++) {
        bias1[t] = b1[(2 * wave + t) * 16 + col];
        bias2[t] = b2[(2 * wave + t) * 16 + col];
    }
    float cx = csum[0] * (1.0f / NN), cy = csum[1] * (1.0f / NN), cz = csum[2] * (1.0f / NN);
    uint4 z = {0u, 0u, 0u, 0u};
    for (int s2 = tid; s2 < 288; s2 += 256) *(uint4*)(feat_s + s2 * 8) = z;  // zero K-pad

    for (int it = 0; it < 4; it++) {
        const int base = blockIdx.x * 128 + it * 32;
        if (base >= NN) break;
        __syncthreads();
        if (tid < 32) {
            int n = base + tid; if (n > NN - 1) n = NN - 1;
            float v[23];
            v[0] = vel[3 * n]; v[1] = vel[3 * n + 1]; v[2] = vel[3 * n + 2];
            v[3] = pos[3 * n] - cx; v[4] = pos[3 * n + 1] - cy; v[5] = pos[3 * n + 2] - cz;
            v[6] = degf[n];
            int rb = rid[n] * 16;
#pragma unroll
            for (int k = 0; k < 16; k++) v[7 + k] = remb[rb + k];
            unsigned short* f = feat_s + tid * 72;
#pragma unroll
            for (int k = 0; k < 23; k++) {
                unsigned short h = f2bf(v[k]);
                f[k] = h; f[32 + k] = f2bf(v[k] - bflo(h));
            }
        }
        __syncthreads();
        f4v acc[2][2];
#pragma unroll
        for (int mt = 0; mt < 2; mt++)
#pragma unroll
            for (int t = 0; t < 2; t++) acc[mt][t] = (f4v){0.f, 0.f, 0.f, 0.f};
        {
            bf8v a0h = *(const bf8v*)(feat_s + col * 72 + quad * 8);
            bf8v a1h = *(const bf8v*)(feat_s + (16 + col) * 72 + quad * 8);
            bf8v a0l = *(const bf8v*)(feat_s + col * 72 + 32 + quad * 8);
            bf8v a1l = *(const bf8v*)(feat_s + (16 + col) * 72 + 32 + quad * 8);
#pragma unroll
            for (int t = 0; t < 2; t++) {
                acc[0][t] = __builtin_amdgcn_mfma_f32_16x16x32_bf16(a0h, W1H[t], acc[0][t], 0, 0, 0);
                acc[1][t] = __builtin_amdgcn_mfma_f32_16x16x32_bf16(a1h, W1H[t], acc[1][t], 0, 0, 0);
                acc[0][t] = __builtin_amdgcn_mfma_f32_16x16x32_bf16(a0l, W1H[t], acc[0][t], 0, 0, 0);
                acc[1][t] = __builtin_amdgcn_mfma_f32_16x16x32_bf16(a1l, W1H[t], acc[1][t], 0, 0, 0);
                acc[0][t] = __builtin_amdgcn_mfma_f32_16x16x32_bf16(a0h, W1L[t], acc[0][t], 0, 0, 0);
                acc[1][t] = __builtin_amdgcn_mfma_f32_16x16x32_bf16(a1h, W1L[t], acc[1][t], 0, 0, 0);
            }
        }
#pragma unroll
        for (int mt = 0; mt < 2; mt++)
#pragma unroll
            for (int t = 0; t < 2; t++) {
                const int nc = (2 * wave + t) * 16 + col;
#pragma unroll
                for (int r = 0; r < 4; r++) {
                    float h = fmaxf(acc[mt][t][r] + bias1[t], 0.f);
                    unsigned short hh = f2bf(h);
                    hid_s[(mt * 16 + quad * 4 + r) * 264 + nc] = hh;
                    hid_s[(mt * 16 + quad * 4 + r) * 264 + 128 + nc] = f2bf(h - bflo(hh));
                }
            }
        __syncthreads();
#pragma unroll
        for (int mt = 0; mt < 2; mt++)
#pragma unroll
            for (int t = 0; t < 2; t++) acc[mt][t] = (f4v){0.f, 0.f, 0.f, 0.f};
#pragma unroll
        for (int kt = 0; kt < 8; kt++) {
            int w = kt & 3;
            bf8v a0 = *(const bf8v*)(hid_s + col * 264 + kt * 32 + quad * 8);
            bf8v a1 = *(const bf8v*)(hid_s + (16 + col) * 264 + kt * 32 + quad * 8);
#pragma unroll
            for (int t = 0; t < 2; t++) {
                acc[0][t] = __builtin_amdgcn_mfma_f32_16x16x32_bf16(a0, W2H[w][t], acc[0][t], 0, 0, 0);
                acc[1][t] = __builtin_amdgcn_mfma_f32_16x16x32_bf16(a1, W2H[w][t], acc[1][t], 0, 0, 0);
            }
        }
#pragma unroll
        for (int kt = 0; kt < 4; kt++) {
            bf8v a0 = *(const bf8v*)(hid_s + col * 264 + kt * 32 + quad * 8);
            bf8v a1 = *(const bf8v*)(hid_s + (16 + col) * 264 + kt * 32 + quad * 8);
#pragma unroll
            for (int t = 0; t < 2; t++) {
                acc[0][t] = __builtin_amdgcn_mfma_f32_16x16x32_bf16(a0, W2L[kt][t], acc[0][t], 0, 0, 0);
                acc[1][t] = __builtin_amdgcn_mfma_f32_16x16x32_bf16(a1, W2L[kt][t], acc[1][t], 0, 0, 0);
            }
        }
        __syncthreads();
#pragma unroll
        for (int mt = 0; mt < 2; mt++)
#pragma unroll
            for (int t = 0; t < 2; t++) {
                const int nc = (2 * wave + t) * 16 + col;
#pragma unroll
                for (int r = 0; r < 4; r++) {
                    const int row = mt * 16 + quad * 4 + r;
                    float v = acc[mt][t][r] + bias2[t];
                    if (base + row < NN) nl[(size_t)(base + row) * 128 + nc] = v;
                    hid_s[row * 264 + nc] = f2bf(v);
                }
            }
        __syncthreads();
#pragma unroll
        for (int p = 0; p < 2; p++) {
            int s2 = p * 256 + tid, e = s2 >> 4, c16 = s2 & 15;
            if (base + e < NN)
                *(uint4*)(nlb + (size_t)(base + e) * 128 + c16 * 8) =
                    *(const uint4*)(hid_s + e * 264 + c16 * 8);
        }
    }
}

// ---------------- MFMA edge encoder (split-precision): feat(9 pad 32, hi|lo) -> 128 -> 128 ----------------
// Processes edges in CSR-permuted order via snd_p/rcv_p; writes el[p].

__global__ __launch_bounds__(256) void k_edge_enc_m(
    const float* __restrict__ pos, const float* __restrict__ vel,
    const int* __restrict__ rid, const int* __restrict__ snd, const int* __restrict__ rcv,
    const unsigned short* __restrict__ w1h, const unsigned short* __restrict__ w1l,
    const float* __restrict__ b1,
    const unsigned short* __restrict__ w2h, const unsigned short* __restrict__ w2l,
    const float* __restrict__ b2,
    unsigned short* __restrict__ el) {
    __shared__ __align__(16) unsigned short feat_s[32 * 72];
    __shared__ __align__(16) unsigned short hid_s[32 * 264];
    const int tid = threadIdx.x, wave = tid >> 6, lane = tid & 63;
    const int col = lane & 15, quad = lane >> 4;
    bf8v W1H[2], W1L[2], W2H[4][2], W2L[4][2];
#pragma unroll
    for (int t = 0; t < 2; t++) {
        W1H[t] = *(const bf8v*)(w1h + ((size_t)(2 * wave + t) * 64 + lane) * 8);
        W1L[t] = *(const bf8v*)(w1l + ((size_t)(2 * wave + t) * 64 + lane) * 8);
    }
#pragma unroll
    for (int kt = 0; kt < 4; kt++)
#pragma unroll
        for (int t = 0; t < 2; t++) {
            W2H[kt][t] = *(const bf8v*)(w2h + ((size_t)(kt * 8 + 2 * wave + t) * 64 + lane) * 8);
            W2L[kt][t] = *(const bf8v*)(w2l + ((size_t)(kt * 8 + 2 * wave + t) * 64 + lane) * 8);
        }
    float bias1[2], bias2[2];
#pragma unroll
    for (int t = 0; t < 2; t++) {
        bias1[t] = b1[(2 * wave + t) * 16 + col];
        bias2[t] = b2[(2 * wave + t) * 16 + col];
    }
    uint4 z = {0u, 0u, 0u, 0u};
    for (int s2 = tid; s2 < 288; s2 += 256) *(uint4*)(feat_s + s2 * 8) = z;

    for (int it = 0; it < 4; it++) {
        const int base = blockIdx.x * 128 + it * 32;
        __syncthreads();
        if (tid < 32) {
            int e = base + tid;
            int s = snd[e], r = rcv[e];
            float v[9];
            v[0] = pos[3 * s] - pos[3 * r]; v[1] = pos[3 * s + 1] - pos[3 * r + 1]; v[2] = pos[3 * s + 2] - pos[3 * r + 2];
            v[3] = vel[3 * s] - vel[3 * r]; v[4] = vel[3 * s + 1] - vel[3 * r + 1]; v[5] = vel[3 * s + 2] - vel[3 * r + 2];
            float sq = v[0] * v[0] + v[1] * v[1] + v[2] * v[2];
            v[6] = sqrtf(sq); v[7] = sq;
            v[8] = (rid[s] == rid[r]) ? 1.f : 0.f;
            unsigned short* f = feat_s + tid * 72;
#pragma unroll
            for (int k = 0; k < 9; k++) {
                unsigned short h = f2bf(v[k]);
                f[k] = h; f[32 + k] = f2bf(v[k] - bflo(h));
            }
        }
        __syncthreads();
        f4v acc[2][2];
#pragma unroll
        for (int mt = 0; mt < 2; mt++)
#pragma unroll
            for (int t = 0; t < 2; t++) acc[mt][t] = (f4v){0.f, 0.f, 0.f, 0.f};
        {
            bf8v a0h = *(const bf8v*)(feat_s + col * 72 + quad * 8);
            bf8v a1h = *(const bf8v*)(feat_s + (16 + col) * 72 + quad * 8);
            bf8v a0l = *(const bf8v*)(feat_s + col * 72 + 32 + quad * 8);
            bf8v a1l = *(const bf8v*)(feat_s + (16 + col) * 72 + 32 + quad * 8);
#pragma unroll
            for (int t = 0; t < 2; t++) {
                acc[0][t] = __builtin_amdgcn_mfma_f32_16x16x32_bf16(a0h, W1H[t], acc[0][t], 0, 0, 0);
                acc[1][t] = __builtin_amdgcn_mfma_f32_16x16x32_bf16(a1h, W1H[t], acc[1][t], 0, 0, 0);
                acc[0][t] = __builtin_amdgcn_mfma_f32_16x16x32_bf16(a0l, W1H[t], acc[0][t], 0, 0, 0);
                acc[1][t] = __builtin_amdgcn_mfma_f32_16x16x32_bf16(a1l, W1H[t], acc[1][t], 0, 0, 0);
                acc[0][t] = __builtin_amdgcn_mfma_f32_16x16x32_bf16(a0h, W1L[t], acc[0][t], 0, 0, 0);
                acc[1][t] = __builtin_amdgcn_mfma_f32_16x16x32_bf16(a1h, W1L[t], acc[1][t], 0, 0, 0);
            }
        }
#pragma unroll
        for (int mt = 0; mt < 2; mt++)
#pragma unroll
            for (int t = 0; t < 2; t++) {
                const int nc = (2 * wave + t) * 16 + col;
#pragma unroll
                for (int r = 0; r < 4; r++) {
                    float h = fmaxf(acc[mt][t][r] + bias1[t], 0.f);
                    unsigned short hh = f2bf(h);
                    hid_s[(mt * 16 + quad * 4 + r) * 264 + nc] = hh;
                    hid_s[(mt * 16 + quad * 4 + r) * 264 + 128 + nc] = f2bf(h - bflo(hh));
                }
            }
        __syncthreads();
#pragma unroll
        for (int mt = 0; mt < 2; mt++)
#pragma unroll
            for (int t = 0; t < 2; t++) acc[mt][t] = (f4v){0.f, 0.f, 0.f, 0.f};
#pragma unroll
        for (int kt = 0; kt < 8; kt++) {
            int w = kt & 3;
            bf8v a0 = *(const bf8v*)(hid_s + col * 264 + kt * 32 + quad * 8);
            bf8v a1 = *(const bf8v*)(hid_s + (16 + col) * 264 + kt * 32 + quad * 8);
#pragma unroll
            for (int t = 0; t < 2; t++) {
                acc[0][t] = __builtin_amdgcn_mfma_f32_16x16x32_bf16(a0, W2H[w][t], acc[0][t], 0, 0, 0);
                acc[1][t] = __builtin_amdgcn_mfma_f32_16x16x32_bf16(a1, W2H[w][t], acc[1][t], 0, 0, 0);
            }
        }
#pragma unroll
        for (int kt = 0; kt < 4; kt++) {
            bf8v a0 = *(const bf8v*)(hid_s + col * 264 + kt * 32 + quad * 8);
            bf8v a1 = *(const bf8v*)(hid_s + (16 + col) * 264 + kt * 32 + quad * 8);
#pragma unroll
            for (int t = 0; t < 2; t++) {
                acc[0][t] = __builtin_amdgcn_mfma_f32_16x16x32_bf16(a0, W2L[kt][t], acc[0][t], 0, 0, 0);
                acc[1][t] = __builtin_amdgcn_mfma_f32_16x16x32_bf16(a1, W2L[kt][t], acc[1][t], 0, 0, 0);
            }
        }
        __syncthreads();
#pragma unroll
        for (int mt = 0; mt < 2; mt++)
#pragma unroll
            for (int t = 0; t < 2; t++) {
                const int nc = (2 * wave + t) * 16 + col;
#pragma unroll
                for (int r = 0; r < 4; r++)
                    hid_s[(mt * 16 + quad * 4 + r) * 264 + nc] = f2bf(acc[mt][t][r] + bias2[t]);
            }
        __syncthreads();
#pragma unroll
        for (int p = 0; p < 2; p++) {
            int s2 = p * 256 + tid, e = s2 >> 4, c16 = s2 & 15;
            *(uint4*)(el + (size_t)(base + e) * 128 + c16 * 8) =
                *(const uint4*)(hid_s + e * 264 + c16 * 8);
        }
    }
}

// ---------------- MFMA edge processor step (structure unchanged; edges in CSR order) ----------------

__global__ __launch_bounds__(256) void k_edge_step(
    unsigned short* __restrict__ el, const unsigned short* __restrict__ nlb,
    const int* __restrict__ snd, const int* __restrict__ rcv,
    const unsigned short* __restrict__ w1f, const float* __restrict__ b1,
    const unsigned short* __restrict__ w2f, const float* __restrict__ b2) {
    __shared__ __align__(16) unsigned short inl_s[32 * 392];
    __shared__ __align__(16) unsigned short hid_s[32 * 136];
    __shared__ int s_idx[64];
    const int tid = threadIdx.x;
    const int wave = tid >> 6, lane = tid & 63;
    const int col = lane & 15, quad = lane >> 4;

    bf8v W1[12][2], W2[4][2];
#pragma unroll
    for (int kt = 0; kt < 12; kt++)
#pragma unroll
        for (int t = 0; t < 2; t++)
            W1[kt][t] = *(const bf8v*)(w1f + ((size_t)(kt * 8 + 2 * wave + t) * 64 + lane) * 8);
#pragma unroll
    for (int kt = 0; kt < 4; kt++)
#pragma unroll
        for (int t = 0; t < 2; t++)
            W2[kt][t] = *(const bf8v*)(w2f + ((size_t)(kt * 8 + 2 * wave + t) * 64 + lane) * 8);
    float bias1[2], bias2[2];
#pragma unroll
    for (int t = 0; t < 2; t++) {
        bias1[t] = b1[(2 * wave + t) * 16 + col];
        bias2[t] = b2[(2 * wave + t) * 16 + col];
    }

    for (int it = 0; it < 4; it++) {
        const int base = blockIdx.x * 128 + it * 32;
        if (tid < 64) s_idx[tid] = (tid < 32) ? snd[base + tid] : rcv[base + tid - 32];
        __syncthreads();
#pragma unroll
        for (int p = 0; p < 2; p++) {
            int s = p * 256 + tid, e = s >> 4, c16 = s & 15;
            *(uint4*)(inl_s + e * 392 + c16 * 8) =
                *(const uint4*)(el + (size_t)(base + e) * 128 + c16 * 8);
            *(uint4*)(inl_s + e * 392 + 128 + c16 * 8) =
                *(const uint4*)(nlb + (size_t)s_idx[e] * 128 + c16 * 8);
            *(uint4*)(inl_s + e * 392 + 256 + c16 * 8) =
                *(const uint4*)(nlb + (size_t)s_idx[32 + e] * 128 + c16 * 8);
        }
        __syncthreads();

        f4v acc[2][2];
#pragma unroll
        for (int mt = 0; mt < 2; mt++)
#pragma unroll
            for (int t = 0; t < 2; t++) acc[mt][t] = (f4v){0.f, 0.f, 0.f, 0.f};
#pragma unroll
        for (int kt = 0; kt < 12; kt++) {
            bf8v a0 = *(const bf8v*)(inl_s + col * 392 + kt * 32 + quad * 8);
            bf8v a1 = *(const bf8v*)(inl_s + (16 + col) * 392 + kt * 32 + quad * 8);
            acc[0][0] = __builtin_amdgcn_mfma_f32_16x16x32_bf16(a0, W1[kt][0], acc[0][0], 0, 0, 0);
            acc[0][1] = __builtin_amdgcn_mfma_f32_16x16x32_bf16(a0, W1[kt][1], acc[0][1], 0, 0, 0);
            acc[1][0] = __builtin_amdgcn_mfma_f32_16x16x32_bf16(a1, W1[kt][0], acc[1][0], 0, 0, 0);
            acc[1][1] = __builtin_amdgcn_mfma_f32_16x16x32_bf16(a1, W1[kt][1], acc[1][1], 0, 0, 0);
        }
#pragma unroll
        for (int mt = 0; mt < 2; mt++)
#pragma unroll
            for (int t = 0; t < 2; t++) {
                const int nc = (2 * wave + t) * 16 + col;
#pragma unroll
                for (int r = 0; r < 4; r++) {
                    float v = fmaxf(acc[mt][t][r] + bias1[t], 0.f);
                    hid_s[(mt * 16 + quad * 4 + r) * 136 + nc] = f2bf(v);
                }
            }
        __syncthreads();

#pragma unroll
        for (int mt = 0; mt < 2; mt++)
#pragma unroll
            for (int t = 0; t < 2; t++) acc[mt][t] = (f4v){0.f, 0.f, 0.f, 0.f};
#pragma unroll
        for (int kt = 0; kt < 4; kt++) {
            bf8v a0 = *(const bf8v*)(hid_s + col * 136 + kt * 32 + quad * 8);
            bf8v a1 = *(const bf8v*)(hid_s + (16 + col) * 136 + kt * 32 + quad * 8);
            acc[0][0] = __builtin_amdgcn_mfma_f32_16x16x32_bf16(a0, W2[kt][0], acc[0][0], 0, 0, 0);
            acc[0][1] = __builtin_amdgcn_mfma_f32_16x16x32_bf16(a0, W2[kt][1], acc[0][1], 0, 0, 0);
            acc[1][0] = __builtin_amdgcn_mfma_f32_16x16x32_bf16(a1, W2[kt][0], acc[1][0], 0, 0, 0);
            acc[1][1] = __builtin_amdgcn_mfma_f32_16x16x32_bf16(a1, W2[kt][1], acc[1][1], 0, 0, 0);
        }
        __syncthreads();
#pragma unroll
        for (int mt = 0; mt < 2; mt++)
#pragma unroll
            for (int t = 0; t < 2; t++) {
                const int nc = (2 * wave + t) * 16 + col;
#pragma unroll
                for (int r = 0; r < 4; r++) {
                    const int row = mt * 16 + quad * 4 + r;
                    float v = acc[mt][t][r] + bias2[t] + bflo((unsigned int)inl_s[row * 392 + nc]);
                    hid_s[row * 136 + nc] = f2bf(v);
                }
            }
        __syncthreads();
#pragma unroll
        for (int p = 0; p < 2; p++) {
            int s = p * 256 + tid, e = s >> 4, c16 = s & 15;
            *(uint4*)(el + (size_t)(base + e) * 128 + c16 * 8) =
                *(const uint4*)(hid_s + e * 136 + c16 * 8);
        }
    }
}

// ---------------- shared node-MLP tile (split-precision), called after A staged in LDS ----------------

__device__ __forceinline__ void node_mlp_tile(
    const int base, const int tid, const int wave, const int col, const int quad,
    unsigned short* __restrict__ a_s, unsigned short* __restrict__ hid_s,
    const bf8v (&W1H)[8][2], const bf8v (&W1L)[8][2],
    const bf8v (&W2H)[4][2], const bf8v (&W2L)[4][2],
    const float (&bias1)[2], const float (&bias2)[2],
    float* __restrict__ nl, unsigned short* __restrict__ nlb) {
    f4v acc[2][2];
#pragma unroll
    for (int mt = 0; mt < 2; mt++)
#pragma unroll
        for (int t = 0; t < 2; t++) acc[mt][t] = (f4v){0.f, 0.f, 0.f, 0.f};
#pragma unroll
    for (int kt = 0; kt < 16; kt++) {
        int w = (kt & 3) + ((kt >> 3) << 2);  // hi/lo halves share W1H frags
        bf8v a0 = *(const bf8v*)(a_s + col * 520 + kt * 32 + quad * 8);
        bf8v a1 = *(const bf8v*)(a_s + (16 + col) * 520 + kt * 32 + quad * 8);
#pragma unroll
        for (int t = 0; t < 2; t++) {
            acc[0][t] = __builtin_amdgcn_mfma_f32_16x16x32_bf16(a0, W1H[w][t], acc[0][t], 0, 0, 0);
            acc[1][t] = __builtin_amdgcn_mfma_f32_16x16x32_bf16(a1, W1H[w][t], acc[1][t], 0, 0, 0);
        }
    }
#pragma unroll
    for (int kt = 0; kt < 8; kt++) {  // W1L on hi segments (nl_hi: kt 0..3, agg_hi: kt 8..11)
        int ka = (kt < 4) ? kt : kt + 4;
        bf8v a0 = *(const bf8v*)(a_s + col * 520 + ka * 32 + quad * 8);
        bf8v a1 = *(const bf8v*)(a_s + (16 + col) * 520 + ka * 32 + quad * 8);
#pragma unroll
        for (int t = 0; t < 2; t++) {
            acc[0][t] = __builtin_amdgcn_mfma_f32_16x16x32_bf16(a0, W1L[kt][t], acc[0][t], 0, 0, 0);
            acc[1][t] = __builtin_amdgcn_mfma_f32_16x16x32_bf16(a1, W1L[kt][t], acc[1][t], 0, 0, 0);
        }
    }
#pragma unroll
    for (int mt = 0; mt < 2; mt++)
#pragma unroll
        for (int t = 0; t < 2; t++) {
            const int nc = (2 * wave + t) * 16 + col;
#pragma unroll
            for (int r = 0; r < 4; r++) {
                float h = fmaxf(acc[mt][t][r] + bias1[t], 0.f);
                unsigned short hh = f2bf(h);
                hid_s[(mt * 16 + quad * 4 + r) * 264 + nc] = hh;
                hid_s[(mt * 16 + quad * 4 + r) * 264 + 128 + nc] = f2bf(h - bflo(hh));
            }
        }
    __syncthreads();
#pragma unroll
    for (int mt = 0; mt < 2; mt++)
#pragma unroll
        for (int t = 0; t < 2; t++) acc[mt][t] = (f4v){0.f, 0.f, 0.f, 0.f};
#pragma unroll
    for (int kt = 0; kt < 8; kt++) {
        int w = kt & 3;
        bf8v a0 = *(const bf8v*)(hid_s + col * 264 + kt * 32 + quad * 8);
        bf8v a1 = *(const bf8v*)(hid_s + (16 + col) * 264 + kt * 32 + quad * 8);
#pragma unroll
        for (int t = 0; t < 2; t++) {
            acc[0][t] = __builtin_amdgcn_mfma_f32_16x16x32_bf16(a0, W2H[w][t], acc[0][t], 0, 0, 0);
            acc[1][t] = __builtin_amdgcn_mfma_f32_16x16x32_bf16(a1, W2H[w][t], acc[1][t], 0, 0, 0);
        }
    }
#pragma unroll
    for (int kt = 0; kt < 4; kt++) {
        bf8v a0 = *(const bf8v*)(hid_s + col * 264 + kt * 32 + quad * 8);
        bf8v a1 = *(const bf8v*)(hid_s + (16 + col) * 264 + kt * 32 + quad * 8);
#pragma unroll
        for (int t = 0; t < 2; t++) {
            acc[0][t] = __builtin_amdgcn_mfma_f32_16x16x32_bf16(a0, W2L[kt][t], acc[0][t], 0, 0, 0);
            acc[1][t] = __builtin_amdgcn_mfma_f32_16x16x32_bf16(a1, W2L[kt][t], acc[1][t], 0, 0, 0);
        }
    }
    __syncthreads();
#pragma unroll
    for (int mt = 0; mt < 2; mt++)
#pragma unroll
        for (int t = 0; t < 2; t++) {
            const int nc = (2 * wave + t) * 16 + col;
#pragma unroll
            for (int r = 0; r < 4; r++) {
                const int row = mt * 16 + quad * 4 + r;
                int n = base + row, ncl = (n < NN) ? n : NN - 1;
                float v = acc[mt][t][r] + bias2[t] + nl[(size_t)ncl * 128 + nc];
                if (n < NN) nl[(size_t)n * 128 + nc] = v;
                hid_s[row * 264 + nc] = f2bf(v);
            }
        }
    __syncthreads();
#pragma unroll
    for (int p = 0; p < 2; p++) {
        int s2 = p * 256 + tid, e = s2 >> 4, cc = s2 & 15;
        if (base + e < NN)
            *(uint4*)(nlb + (size_t)(base + e) * 128 + cc * 8) =
                *(const uint4*)(hid_s + e * 264 + cc * 8);
    }
}

// ---------------- node step: sequential CSR gather (el in receiver order) + split-precision MLP ----------------
// 64 nodes/block (2 tiles), grid 782. Gather reads el rows row_start[n]..row_start[n+1] contiguously.

__global__ __launch_bounds__(256) void k_node_step_p(
    float* __restrict__ nl, unsigned short* __restrict__ nlb,
    const unsigned short* __restrict__ el, const int* __restrict__ row_start,
    const unsigned short* __restrict__ w1h, const unsigned short* __restrict__ w1l,
    const float* __restrict__ b1,
    const unsigned short* __restrict__ w2h, const unsigned short* __restrict__ w2l,
    const float* __restrict__ b2) {
    __shared__ __align__(16) unsigned short a_s[32 * 520];
    __shared__ __align__(16) unsigned short hid_s[32 * 264];
    const int tid = threadIdx.x, wave = tid >> 6, lane = tid & 63;
    const int col = lane & 15, quad = lane >> 4;
    const int sub = lane >> 4, c16g = lane & 15;
    bf8v W1H[8][2], W1L[8][2], W2H[4][2], W2L[4][2];
#pragma unroll
    for (int kt = 0; kt < 8; kt++)
#pragma unroll
        for (int t = 0; t < 2; t++) {
            W1H[kt][t] = *(const bf8v*)(w1h + ((size_t)(kt * 8 + 2 * wave + t) * 64 + lane) * 8);
            W1L[kt][t] = *(const bf8v*)(w1l + ((size_t)(kt * 8 + 2 * wave + t) * 64 + lane) * 8);
        }
#pragma unroll
    for (int kt = 0; kt < 4; kt++)
#pragma unroll
        for (int t = 0; t < 2; t++) {
            W2H[kt][t] = *(const bf8v*)(w2h + ((size_t)(kt * 8 + 2 * wave + t) * 64 + lane) * 8);
            W2L[kt][t] = *(const bf8v*)(w2l + ((size_t)(kt * 8 + 2 * wave + t) * 64 + lane) * 8);
        }
    float bias1[2], bias2[2];
#pragma unroll
    for (int t = 0; t < 2; t++) {
        bias1[t] = b1[(2 * wave + t) * 16 + col];
        bias2[t] = b2[(2 * wave + t) * 16 + col];
    }
    for (int it = 0; it < 2; it++) {
        const int base = blockIdx.x * 64 + it * 32;
        if (base >= NN) break;
        __syncthreads();
        // stage nl fp32 -> hi/lo
#pragma unroll
        for (int p = 0; p < 4; p++) {
            int s2 = p * 256 + tid, e = s2 >> 5, c4 = s2 & 31;
            int n = base + e; if (n > NN - 1) n = NN - 1;
            float4 v = *(const float4*)(nl + (size_t)n * 128 + c4 * 4);
            ushort4 hi, lo;
            hi.x = f2bf(v.x); lo.x = f2bf(v.x - bflo(hi.x));
            hi.y = f2bf(v.y); lo.y = f2bf(v.y - bflo(hi.y));
            hi.z = f2bf(v.z); lo.z = f2bf(v.z - bflo(hi.z));
            hi.w = f2bf(v.w); lo.w = f2bf(v.w - bflo(hi.w));
            *(ushort4*)(a_s + e * 520 + c4 * 4) = hi;
            *(ushort4*)(a_s + e * 520 + 128 + c4 * 4) = lo;
        }
        // sequential gather: node n's in-edges are el rows st..en (contiguous)
        for (int i = 0; i < 8; i++) {
            int e = wave * 8 + i, n = base + e;
            if (n < NN) {
                int st = row_start[n], en = row_start[n + 1];
                float s[8];
#pragma unroll
                for (int k = 0; k < 8; k++) s[k] = 0.f;
                for (int q = st + sub; q < en; q += 4) {
                    uint4 v = *(const uint4*)(el + (size_t)q * 128 + c16g * 8);
                    s[0] += bflo(v.x); s[1] += bfhi(v.x);
                    s[2] += bflo(v.y); s[3] += bfhi(v.y);
                    s[4] += bflo(v.z); s[5] += bfhi(v.z);
                    s[6] += bflo(v.w); s[7] += bfhi(v.w);
                }
#pragma unroll
                for (int k = 0; k < 8; k++) {
                    s[k] += __shfl_xor(s[k], 16);
                    s[k] += __shfl_xor(s[k], 32);
                }
                if (sub == 0) {
                    u16x8 h8, l8;
#pragma unroll
                    for (int k = 0; k < 8; k++) {
                        h8[k] = f2bf(s[k]);
                        l8[k] = f2bf(s[k] - bflo((unsigned int)h8[k]));
                    }
                    *(u16x8*)(a_s + e * 520 + 256 + c16g * 8) = h8;
                    *(u16x8*)(a_s + e * 520 + 384 + c16g * 8) = l8;
                }
            }
        }
        __syncthreads();
        node_mlp_tile(base, tid, wave, col, quad, a_s, hid_s,
                      W1H, W1L, W2H, W2L, bias1, bias2, nl, nlb);
    }
}

// ---------------- decoder: 128 -> 128 -> 3 (fp32 VALU, reads fp32 nl) ----------------

__global__ __launch_bounds__(128) void k_decode(
    const float* __restrict__ nl,
    const float* __restrict__ w1, const float* __restrict__ b1,
    const float* __restrict__ w2, const float* __restrict__ b2,
    float* __restrict__ out) {
    __shared__ float inl[16][128];
    __shared__ float hid[16][128];
    int j = threadIdx.x;
    int base = blockIdx.x * 16;
    for (int e = 0; e < 16; e++) inl[e][j] = nl[(size_t)(base + e) * 128 + j];
    __syncthreads();
    float acc[16];
#pragma unroll
    for (int e = 0; e < 16; e++) acc[e] = b1[j];
    for (int kc = 0; kc < 16; kc++) {
        float w[8];
#pragma unroll
        for (int t = 0; t < 8; t++) w[t] = w1[(kc * 8 + t) * 128 + j];
#pragma unroll
        for (int e = 0; e < 16; e++) {
            float4 h0 = *(const float4*)&inl[e][kc * 8];
            float4 h1 = *(const float4*)&inl[e][kc * 8 + 4];
            acc[e] = fmaf(h0.x, w[0], acc[e]); acc[e] = fmaf(h0.y, w[1], acc[e]);
            acc[e] = fmaf(h0.z, w[2], acc[e]); acc[e] = fmaf(h0.w, w[3], acc[e]);
            acc[e] = fmaf(h1.x, w[4], acc[e]); acc[e] = fmaf(h1.y, w[5], acc[e]);
            acc[e] = fmaf(h1.z, w[6], acc[e]); acc[e] = fmaf(h1.w, w[7], acc[e]);
        }
    }
#pragma unroll
    for (int e = 0; e < 16; e++) hid[e][j] = fmaxf(acc[e], 0.f);
    __syncthreads();
    if (j < 48) {
        int e = j / 3, ch = j - 3 * (j / 3);
        float s = b2[ch];
        for (int k = 0; k < 128; k++) s = fmaf(hid[e][k], w2[k * 3 + ch], s);
        out[(size_t)(base + e) * 3 + ch] = s;
    }
}

// ---------------- launch ----------------

extern "C" void kernel_launch(void* const* d_in, const int* in_sizes, int n_in,
                              void* d_out, int out_size, void* d_ws, size_t ws_size,
                              hipStream_t stream) {
    (void)in_sizes; (void)n_in; (void)out_size; (void)ws_size;
    const float* pos   = (const float*)d_in[0];
    const float* vel   = (const float*)d_in[1];
    const int*   rid   = (const int*)d_in[2];
    const int*   snd   = (const int*)d_in[3];
    const int*   rcv   = (const int*)d_in[4];
    const float* remb  = (const float*)d_in[5];
    const float* ne_w1 = (const float*)d_in[6];
    const float* ne_b1 = (const float*)d_in[7];
    const float* ne_w2 = (const float*)d_in[8];
    const float* ne_b2 = (const float*)d_in[9];
    const float* ee_w1 = (const float*)d_in[10];
    const float* ee_b1 = (const float*)d_in[11];
    const float* ee_w2 = (const float*)d_in[12];
    const float* ee_b2 = (const float*)d_in[13];
    const float* pe_w1 = (const float*)d_in[14];
    const float* pe_b1 = (const float*)d_in[15];
    const float* pe_w2 = (const float*)d_in[16];
    const float* pe_b2 = (const float*)d_in[17];
    const float* pn_w1 = (const float*)d_in[18];
    const float* pn_b1 = (const float*)d_in[19];
    const float* pn_w2 = (const float*)d_in[20];
    const float* pn_b2 = (const float*)d_in[21];
    const float* de_w1 = (const float*)d_in[22];
    const float* de_b1 = (const float*)d_in[23];
    const float* de_w2 = (const float*)d_in[24];
    const float* de_b2 = (const float*)d_in[25];
    float* out = (float*)d_out;

    // workspace carve (~253.9 MB — under the 256.2 MB proven available in round 1)
    char* p = (char*)d_ws;
    auto carve = [&](size_t bytes) { void* q = (void*)p; p += (bytes + 15) & ~(size_t)15; return q; };
    unsigned short* el    = (unsigned short*)carve((size_t)NE * LDIM * 2);   // 204.8 MB, CSR order
    float*          nl    = (float*)carve((size_t)NN * LDIM * 4);            // 25.6 MB
    unsigned short* nlb   = (unsigned short*)carve((size_t)NN * LDIM * 2);   // 12.8 MB
    unsigned short* w1f_e = (unsigned short*)carve((size_t)NSTEPS * 12 * 8 * 512 * 2);
    unsigned short* w2f_e = (unsigned short*)carve((size_t)NSTEPS * 4 * 8 * 512 * 2);
    unsigned short* w1h_n = (unsigned short*)carve((size_t)NSTEPS * 8 * 8 * 512 * 2);
    unsigned short* w1l_n = (unsigned short*)carve((size_t)NSTEPS * 8 * 8 * 512 * 2);
    unsigned short* w2h_n = (unsigned short*)carve((size_t)NSTEPS * 4 * 8 * 512 * 2);
    unsigned short* w2l_n = (unsigned short*)carve((size_t)NSTEPS * 4 * 8 * 512 * 2);
    unsigned short* eew1h = (unsigned short*)carve((size_t)1 * 8 * 512 * 2);
    unsigned short* eew1l = (unsigned short*)carve((size_t)1 * 8 * 512 * 2);
    unsigned short* eew2h = (unsigned short*)carve((size_t)4 * 8 * 512 * 2);
    unsigned short* eew2l = (unsigned short*)carve((size_t)4 * 8 * 512 * 2);
    unsigned short* new1h = (unsigned short*)carve((size_t)1 * 8 * 512 * 2);
    unsigned short* new1l = (unsigned short*)carve((size_t)1 * 8 * 512 * 2);
    unsigned short* new2h = (unsigned short*)carve((size_t)4 * 8 * 512 * 2);
    unsigned short* new2l = (unsigned short*)carve((size_t)4 * 8 * 512 * 2);
    int*            snd_p = (int*)carve((size_t)NE * 4);                     // 3.2 MB
    int*            rcv_p = (int*)carve((size_t)NE * 4);                     // 3.2 MB
    int*            rs    = (int*)carve((size_t)(NN + 1) * 4);
    int*            cnt   = (int*)carve((size_t)NN * 4);
    int*            cur   = (int*)carve((size_t)NN * 4);
    float*          degf  = (float*)carve((size_t)NN * 4);
    float*          csum  = (float*)carve(16);

    hipMemsetAsync(cnt, 0, (size_t)NN * 4, stream);
    hipMemsetAsync(csum, 0, 16, stream);
    k_hist<<<NE / 256, 256, 0, stream>>>(rcv, cnt);
    k_scan<<<1, 1024, 0, stream>>>(cnt, rs, cur, degf);
    k_center<<<64, 256, 0, stream>>>(pos, csum);
    k_scatter<<<NE / 256, 256, 0, stream>>>(snd, rcv, cur, snd_p, rcv_p);
    k_prep_w<<<NSTEPS * 12 * 8, 64, 0, stream>>>(pe_w1, w1f_e, 12, 384, 0);
    k_prep_w<<<NSTEPS * 4 * 8, 64, 0, stream>>>(pe_w2, w2f_e, 4, 128, 0);
    k_prep_w<<<NSTEPS * 8 * 8, 64, 0, stream>>>(pn_w1, w1h_n, 8, 256, 0);
    k_prep_w<<<NSTEPS * 8 * 8, 64, 0, stream>>>(pn_w1, w1l_n, 8, 256, 1);
    k_prep_w<<<NSTEPS * 4 * 8, 64, 0, stream>>>(pn_w2, w2h_n, 4, 128, 0);
    k_prep_w<<<NSTEPS * 4 * 8, 64, 0, stream>>>(pn_w2, w2l_n, 4, 128, 1);
    k_prep_w<<<8, 64, 0, stream>>>(ee_w1, eew1h, 1, 9, 0);
    k_prep_w<<<8, 64, 0, stream>>>(ee_w1, eew1l, 1, 9, 1);
    k_prep_w<<<4 * 8, 64, 0, stream>>>(ee_w2, eew2h, 4, 128, 0);
    k_prep_w<<<4 * 8, 64, 0, stream>>>(ee_w2, eew2l, 4, 128, 1);
    k_prep_w<<<8, 64, 0, stream>>>(ne_w1, new1h, 1, 23, 0);
    k_prep_w<<<8, 64, 0, stream>>>(ne_w1, new1l, 1, 23, 1);
    k_prep_w<<<4 * 8, 64, 0, stream>>>(ne_w2, new2h, 4, 128, 0);
    k_prep_w<<<4 * 8, 64, 0, stream>>>(ne_w2, new2l, 4, 128, 1);

    k_node_enc_m<<<(NN + 127) / 128, 256, 0, stream>>>(pos, vel, rid, remb, degf, csum,
                                                       new1h, new1l, ne_b1, new2h, new2l, ne_b2, nl, nlb);
    k_edge_enc_m<<<NE / 128, 256, 0, stream>>>(pos, vel, rid, snd_p, rcv_p,
                                               eew1h, eew1l, ee_b1, eew2h, eew2l, ee_b2, el);
    for (int i = 0; i < NSTEPS; i++) {
        k_edge_step<<<NE / 128, 256, 0, stream>>>(el, nlb, snd_p, rcv_p,
            w1f_e + (size_t)i * 12 * 8 * 512, pe_b1 + i * 128,
            w2f_e + (size_t)i * 4 * 8 * 512, pe_b2 + i * 128);
        k_node_step_p<<<(NN + 63) / 64, 256, 0, stream>>>(nl, nlb, el, rs,
            w1h_n + (size_t)i * 8 * 8 * 512, w1l_n + (size_t)i * 8 * 8 * 512, pn_b1 + i * 128,
            w2h_n + (size_t)i * 4 * 8 * 512, w2l_n + (size_t)i * 4 * 8 * 512, pn_b2 + i * 128);
    }
    k_decode<<<NN / 16, 128, 0, stream>>>(nl, de_w1, de_b1, de_w2, de_b2, out);
}

// Round 8
// 2943.863 us; speedup vs baseline: 1.5728x; 1.3041x over previous
//
#include <hip/hip_runtime.h>
#include <hip/hip_bf16.h>

#define NN 50000
#define NE 800000
#define LDIM 128
#define NSTEPS 10

typedef __hip_bfloat16 bf16;
typedef __bf16 bf8v __attribute__((ext_vector_type(8)));
typedef float f4v __attribute__((ext_vector_type(4)));
typedef unsigned short u16x8 __attribute__((ext_vector_type(8)));

__device__ inline float bflo(unsigned int u) {
    union { unsigned int i; float f; } x; x.i = u << 16; return x.f;
}
__device__ inline float bfhi(unsigned int u) {
    union { unsigned int i; float f; } x; x.i = u & 0xffff0000u; return x.f;
}
__device__ inline unsigned short f2bf(float f) {
    __hip_bfloat16 h = __float2bfloat16(f);
    unsigned short u; __builtin_memcpy(&u, &h, 2); return u;
}

// ---------------- CSR build: histogram, scan, scatter (ushort permuted endpoints) ----------------

__global__ void k_hist(const int* __restrict__ rcv, int* __restrict__ cnt) {
    int i = blockIdx.x * 256 + threadIdx.x;
    if (i < NE) atomicAdd(&cnt[rcv[i]], 1);
}

__global__ __launch_bounds__(1024) void k_scan(
    const int* __restrict__ cnt, int* __restrict__ row_start,
    int* __restrict__ cur, float* __restrict__ degf) {
    __shared__ int part[1024];
    const int t = threadIdx.x;
    const int CH = (NN + 1023) / 1024;  // 49
    int b0 = t * CH, b1 = b0 + CH; if (b1 > NN) b1 = NN; if (b0 > NN) b0 = NN;
    int s = 0;
    for (int i = b0; i < b1; i++) s += cnt[i];
    part[t] = s;
    __syncthreads();
    for (int off = 1; off < 1024; off <<= 1) {
        int v = (t >= off) ? part[t - off] : 0;
        __syncthreads();
        part[t] += v;
        __syncthreads();
    }
    int run = part[t] - s;  // exclusive prefix
    for (int i = b0; i < b1; i++) {
        row_start[i] = run; cur[i] = run; degf[i] = (float)cnt[i];
        run += cnt[i];
    }
    if (t == 1023) row_start[NN] = part[1023];
}

// el lives permanently in CSR (receiver-sorted) order; edge p's endpoints snd_p[p]/rcv_p[p] (ushort, NN<65536)
__global__ void k_scatter(const int* __restrict__ snd, const int* __restrict__ rcv,
                          int* __restrict__ cur,
                          unsigned short* __restrict__ snd_p, unsigned short* __restrict__ rcv_p) {
    int i = blockIdx.x * 256 + threadIdx.x;
    if (i < NE) {
        int r = rcv[i];
        int p = atomicAdd(&cur[r], 1);
        snd_p[p] = (unsigned short)snd[i];
        rcv_p[p] = (unsigned short)r;
    }
}

__global__ void k_center(const float* __restrict__ pos, float* __restrict__ csum) {
    __shared__ float s[3][256];
    float a = 0.f, b = 0.f, c = 0.f;
    for (int i = blockIdx.x * 256 + threadIdx.x; i < NN; i += gridDim.x * 256) {
        a += pos[3 * i]; b += pos[3 * i + 1]; c += pos[3 * i + 2];
    }
    int t = threadIdx.x;
    s[0][t] = a; s[1][t] = b; s[2][t] = c;
    __syncthreads();
    for (int off = 128; off > 0; off >>= 1) {
        if (t < off) {
            s[0][t] += s[0][t + off];
            s[1][t] += s[1][t + off];
            s[2][t] += s[2][t + off];
        }
        __syncthreads();
    }
    if (t == 0) {
        atomicAdd(&csum[0], s[0][0]);
        atomicAdd(&csum[1], s[1][0]);
        atomicAdd(&csum[2], s[2][0]);
    }
}

// ---------------- weight prep: fp32 -> bf16 B-frag order; lo=1 emits bf16(x - bf16(x)) ----------------

__global__ void k_prep_w(const float* __restrict__ w, unsigned short* __restrict__ wf,
                         int KT, int Ksrc, int lo) {
    int b = blockIdx.x;
    int s = b / (KT * 8), rem = b % (KT * 8);
    int kt = rem / 8, nt = rem % 8;
    int lane = threadIdx.x, col = lane & 15, quad = lane >> 4;
    const float* W = w + (size_t)s * Ksrc * 128;
    u16x8 o;
#pragma unroll
    for (int jj = 0; jj < 8; jj++) {
        int k = kt * 32 + quad * 8 + jj;
        float x = (k < Ksrc) ? W[(size_t)k * 128 + nt * 16 + col] : 0.f;
        unsigned short h = f2bf(x);
        if (lo) h = f2bf(x - bflo(h));
        o[jj] = h;
    }
    *(u16x8*)(wf + (((size_t)b) * 64 + lane) * 8) = o;
}

// ---------------- CSR aggregation: streaming reduction el (CSR order) -> bf16 agg ----------------
// One wave per node; lane = sub(4) x c16(16); reads are sequential across the whole el array.

__global__ __launch_bounds__(256) void k_agg(
    const unsigned short* __restrict__ el, const int* __restrict__ row_start,
    unsigned short* __restrict__ agg) {
    const int wave = threadIdx.x >> 6, lane = threadIdx.x & 63;
    const int n = blockIdx.x * 4 + wave;
    if (n >= NN) return;
    const int sub = lane >> 4, c16 = lane & 15;
    const int st = row_start[n], en = row_start[n + 1];
    float s[8];
#pragma unroll
    for (int k = 0; k < 8; k++) s[k] = 0.f;
    for (int q = st + sub; q < en; q += 4) {
        uint4 v = *(const uint4*)(el + (size_t)q * 128 + c16 * 8);
        s[0] += bflo(v.x); s[1] += bfhi(v.x);
        s[2] += bflo(v.y); s[3] += bfhi(v.y);
        s[4] += bflo(v.z); s[5] += bfhi(v.z);
        s[6] += bflo(v.w); s[7] += bfhi(v.w);
    }
#pragma unroll
    for (int k = 0; k < 8; k++) {
        s[k] += __shfl_xor(s[k], 16);
        s[k] += __shfl_xor(s[k], 32);
    }
    if (sub == 0) {
        u16x8 o;
#pragma unroll
        for (int k = 0; k < 8; k++) o[k] = f2bf(s[k]);
        *(u16x8*)(agg + (size_t)n * 128 + c16 * 8) = o;
    }
}

// ---------------- MFMA node encoder (split-precision): feat(23 pad 32, hi|lo) -> 128 -> 128 ----------------

__global__ __launch_bounds__(256) void k_node_enc_m(
    const float* __restrict__ pos, const float* __restrict__ vel,
    const int* __restrict__ rid, const float* __restrict__ remb,
    const float* __restrict__ degf, const float* __restrict__ csum,
    const unsigned short* __restrict__ w1h, const unsigned short* __restrict__ w1l,
    const float* __restrict__ b1,
    const unsigned short* __restrict__ w2h, const unsigned short* __restrict__ w2l,
    const float* __restrict__ b2,
    float* __restrict__ nl) {
    __shared__ __align__(16) unsigned short feat_s[32 * 72];   // [hi(32)|lo(32)|pad]
    __shared__ __align__(16) unsigned short hid_s[32 * 264];   // [hi(128)|lo(128)|pad]
    const int tid = threadIdx.x, wave = tid >> 6, lane = tid & 63;
    const int col = lane & 15, quad = lane >> 4;
    bf8v W1H[2], W1L[2], W2H[4][2], W2L[4][2];
#pragma unroll
    for (int t = 0; t < 2; t++) {
        W1H[t] = *(const bf8v*)(w1h + ((size_t)(2 * wave + t) * 64 + lane) * 8);
        W1L[t] = *(const bf8v*)(w1l + ((size_t)(2 * wave + t) * 64 + lane) * 8);
    }
#pragma unroll
    for (int kt = 0; kt < 4; kt++)
#pragma unroll
        for (int t = 0; t < 2; t++) {
            W2H[kt][t] = *(const bf8v*)(w2h + ((size_t)(kt * 8 + 2 * wave + t) * 64 + lane) * 8);
            W2L[kt][t] = *(const bf8v*)(w2l + ((size_t)(kt * 8 + 2 * wave + t) * 64 + lane) * 8);
        }
    float bias1[2], bias2[2];
#pragma unroll
    for (int t = 0; t < 2; t++) {
        bias1[t] = b1[(2 * wave + t) * 16 + col];
        bias2[t] = b2[(2 * wave + t) * 16 + col];
    }
    float cx = csum[0] * (1.0f / NN), cy = csum[1] * (1.0f / NN), cz = csum[2] * (1.0f / NN);
    uint4 z = {0u, 0u, 0u, 0u};
    for (int s2 = tid; s2 < 288; s2 += 256) *(uint4*)(feat_s + s2 * 8) = z;  // zero K-pad

    for (int it = 0; it < 4; it++) {
        const int base = blockIdx.x * 128 + it * 32;
        if (base >= NN) break;
        __syncthreads();
        if (tid < 32) {
            int n = base + tid; if (n > NN - 1) n = NN - 1;
            float v[23];
            v[0] = vel[3 * n]; v[1] = vel[3 * n + 1]; v[2] = vel[3 * n + 2];
            v[3] = pos[3 * n] - cx; v[4] = pos[3 * n + 1] - cy; v[5] = pos[3 * n + 2] - cz;
            v[6] = degf[n];
            int rb = rid[n] * 16;
#pragma unroll
            for (int k = 0; k < 16; k++) v[7 + k] = remb[rb + k];
            unsigned short* f = feat_s + tid * 72;
#pragma unroll
            for (int k = 0; k < 23; k++) {
                unsigned short h = f2bf(v[k]);
                f[k] = h; f[32 + k] = f2bf(v[k] - bflo(h));
            }
        }
        __syncthreads();
        f4v acc[2][2];
#pragma unroll
        for (int mt = 0; mt < 2; mt++)
#pragma unroll
            for (int t = 0; t < 2; t++) acc[mt][t] = (f4v){0.f, 0.f, 0.f, 0.f};
        {
            bf8v a0h = *(const bf8v*)(feat_s + col * 72 + quad * 8);
            bf8v a1h = *(const bf8v*)(feat_s + (16 + col) * 72 + quad * 8);
            bf8v a0l = *(const bf8v*)(feat_s + col * 72 + 32 + quad * 8);
            bf8v a1l = *(const bf8v*)(feat_s + (16 + col) * 72 + 32 + quad * 8);
#pragma unroll
            for (int t = 0; t < 2; t++) {
                acc[0][t] = __builtin_amdgcn_mfma_f32_16x16x32_bf16(a0h, W1H[t], acc[0][t], 0, 0, 0);
                acc[1][t] = __builtin_amdgcn_mfma_f32_16x16x32_bf16(a1h, W1H[t], acc[1][t], 0, 0, 0);
                acc[0][t] = __builtin_amdgcn_mfma_f32_16x16x32_bf16(a0l, W1H[t], acc[0][t], 0, 0, 0);
                acc[1][t] = __builtin_amdgcn_mfma_f32_16x16x32_bf16(a1l, W1H[t], acc[1][t], 0, 0, 0);
                acc[0][t] = __builtin_amdgcn_mfma_f32_16x16x32_bf16(a0h, W1L[t], acc[0][t], 0, 0, 0);
                acc[1][t] = __builtin_amdgcn_mfma_f32_16x16x32_bf16(a1h, W1L[t], acc[1][t], 0, 0, 0);
            }
        }
#pragma unroll
        for (int mt = 0; mt < 2; mt++)
#pragma unroll
            for (int t = 0; t < 2; t++) {
                const int nc = (2 * wave + t) * 16 + col;
#pragma unroll
                for (int r = 0; r < 4; r++) {
                    float h = fmaxf(acc[mt][t][r] + bias1[t], 0.f);
                    unsigned short hh = f2bf(h);
                    hid_s[(mt * 16 + quad * 4 + r) * 264 + nc] = hh;
                    hid_s[(mt * 16 + quad * 4 + r) * 264 + 128 + nc] = f2bf(h - bflo(hh));
                }
            }
        __syncthreads();
#pragma unroll
        for (int mt = 0; mt < 2; mt++)
#pragma unroll
            for (int t = 0; t < 2; t++) acc[mt][t] = (f4v){0.f, 0.f, 0.f, 0.f};
#pragma unroll
        for (int kt = 0; kt < 8; kt++) {
            int w = kt & 3;
            bf8v a0 = *(const bf8v*)(hid_s + col * 264 + kt * 32 + quad * 8);
            bf8v a1 = *(const bf8v*)(hid_s + (16 + col) * 264 + kt * 32 + quad * 8);
#pragma unroll
            for (int t = 0; t < 2; t++) {
                acc[0][t] = __builtin_amdgcn_mfma_f32_16x16x32_bf16(a0, W2H[w][t], acc[0][t], 0, 0, 0);
                acc[1][t] = __builtin_amdgcn_mfma_f32_16x16x32_bf16(a1, W2H[w][t], acc[1][t], 0, 0, 0);
            }
        }
#pragma unroll
        for (int kt = 0; kt < 4; kt++) {
            bf8v a0 = *(const bf8v*)(hid_s + col * 264 + kt * 32 + quad * 8);
            bf8v a1 = *(const bf8v*)(hid_s + (16 + col) * 264 + kt * 32 + quad * 8);
#pragma unroll
            for (int t = 0; t < 2; t++) {
                acc[0][t] = __builtin_amdgcn_mfma_f32_16x16x32_bf16(a0, W2L[kt][t], acc[0][t], 0, 0, 0);
                acc[1][t] = __builtin_amdgcn_mfma_f32_16x16x32_bf16(a1, W2L[kt][t], acc[1][t], 0, 0, 0);
            }
        }
#pragma unroll
        for (int mt = 0; mt < 2; mt++)
#pragma unroll
            for (int t = 0; t < 2; t++) {
                const int nc = (2 * wave + t) * 16 + col;
#pragma unroll
                for (int r = 0; r < 4; r++) {
                    const int row = mt * 16 + quad * 4 + r;
                    if (base + row < NN)
                        nl[(size_t)(base + row) * 128 + nc] = acc[mt][t][r] + bias2[t];
                }
            }
    }
}

// ---------------- MFMA edge encoder (split-precision): feat(9 pad 32, hi|lo) -> 128 -> 128 ----------------

__global__ __launch_bounds__(256) void k_edge_enc_m(
    const float* __restrict__ pos, const float* __restrict__ vel,
    const int* __restrict__ rid,
    const unsigned short* __restrict__ snd, const unsigned short* __restrict__ rcv,
    const unsigned short* __restrict__ w1h, const unsigned short* __restrict__ w1l,
    const float* __restrict__ b1,
    const unsigned short* __restrict__ w2h, const unsigned short* __restrict__ w2l,
    const float* __restrict__ b2,
    unsigned short* __restrict__ el) {
    __shared__ __align__(16) unsigned short feat_s[32 * 72];
    __shared__ __align__(16) unsigned short hid_s[32 * 264];
    const int tid = threadIdx.x, wave = tid >> 6, lane = tid & 63;
    const int col = lane & 15, quad = lane >> 4;
    bf8v W1H[2], W1L[2], W2H[4][2], W2L[4][2];
#pragma unroll
    for (int t = 0; t < 2; t++) {
        W1H[t] = *(const bf8v*)(w1h + ((size_t)(2 * wave + t) * 64 + lane) * 8);
        W1L[t] = *(const bf8v*)(w1l + ((size_t)(2 * wave + t) * 64 + lane) * 8);
    }
#pragma unroll
    for (int kt = 0; kt < 4; kt++)
#pragma unroll
        for (int t = 0; t < 2; t++) {
            W2H[kt][t] = *(const bf8v*)(w2h + ((size_t)(kt * 8 + 2 * wave + t) * 64 + lane) * 8);
            W2L[kt][t] = *(const bf8v*)(w2l + ((size_t)(kt * 8 + 2 * wave + t) * 64 + lane) * 8);
        }
    float bias1[2], bias2[2];
#pragma unroll
    for (int t = 0; t < 2; t++) {
        bias1[t] = b1[(2 * wave + t) * 16 + col];
        bias2[t] = b2[(2 * wave + t) * 16 + col];
    }
    uint4 z = {0u, 0u, 0u, 0u};
    for (int s2 = tid; s2 < 288; s2 += 256) *(uint4*)(feat_s + s2 * 8) = z;

    for (int it = 0; it < 4; it++) {
        const int base = blockIdx.x * 128 + it * 32;
        __syncthreads();
        if (tid < 32) {
            int e = base + tid;
            int s = snd[e], r = rcv[e];
            float v[9];
            v[0] = pos[3 * s] - pos[3 * r]; v[1] = pos[3 * s + 1] - pos[3 * r + 1]; v[2] = pos[3 * s + 2] - pos[3 * r + 2];
            v[3] = vel[3 * s] - vel[3 * r]; v[4] = vel[3 * s + 1] - vel[3 * r + 1]; v[5] = vel[3 * s + 2] - vel[3 * r + 2];
            float sq = v[0] * v[0] + v[1] * v[1] + v[2] * v[2];
            v[6] = sqrtf(sq); v[7] = sq;
            v[8] = (rid[s] == rid[r]) ? 1.f : 0.f;
            unsigned short* f = feat_s + tid * 72;
#pragma unroll
            for (int k = 0; k < 9; k++) {
                unsigned short h = f2bf(v[k]);
                f[k] = h; f[32 + k] = f2bf(v[k] - bflo(h));
            }
        }
        __syncthreads();
        f4v acc[2][2];
#pragma unroll
        for (int mt = 0; mt < 2; mt++)
#pragma unroll
            for (int t = 0; t < 2; t++) acc[mt][t] = (f4v){0.f, 0.f, 0.f, 0.f};
        {
            bf8v a0h = *(const bf8v*)(feat_s + col * 72 + quad * 8);
            bf8v a1h = *(const bf8v*)(feat_s + (16 + col) * 72 + quad * 8);
            bf8v a0l = *(const bf8v*)(feat_s + col * 72 + 32 + quad * 8);
            bf8v a1l = *(const bf8v*)(feat_s + (16 + col) * 72 + 32 + quad * 8);
#pragma unroll
            for (int t = 0; t < 2; t++) {
                acc[0][t] = __builtin_amdgcn_mfma_f32_16x16x32_bf16(a0h, W1H[t], acc[0][t], 0, 0, 0);
                acc[1][t] = __builtin_amdgcn_mfma_f32_16x16x32_bf16(a1h, W1H[t], acc[1][t], 0, 0, 0);
                acc[0][t] = __builtin_amdgcn_mfma_f32_16x16x32_bf16(a0l, W1H[t], acc[0][t], 0, 0, 0);
                acc[1][t] = __builtin_amdgcn_mfma_f32_16x16x32_bf16(a1l, W1H[t], acc[1][t], 0, 0, 0);
                acc[0][t] = __builtin_amdgcn_mfma_f32_16x16x32_bf16(a0h, W1L[t], acc[0][t], 0, 0, 0);
                acc[1][t] = __builtin_amdgcn_mfma_f32_16x16x32_bf16(a1h, W1L[t], acc[1][t], 0, 0, 0);
            }
        }
#pragma unroll
        for (int mt = 0; mt < 2; mt++)
#pragma unroll
            for (int t = 0; t < 2; t++) {
                const int nc = (2 * wave + t) * 16 + col;
#pragma unroll
                for (int r = 0; r < 4; r++) {
                    float h = fmaxf(acc[mt][t][r] + bias1[t], 0.f);
                    unsigned short hh = f2bf(h);
                    hid_s[(mt * 16 + quad * 4 + r) * 264 + nc] = hh;
                    hid_s[(mt * 16 + quad * 4 + r) * 264 + 128 + nc] = f2bf(h - bflo(hh));
                }
            }
        __syncthreads();
#pragma unroll
        for (int mt = 0; mt < 2; mt++)
#pragma unroll
            for (int t = 0; t < 2; t++) acc[mt][t] = (f4v){0.f, 0.f, 0.f, 0.f};
#pragma unroll
        for (int kt = 0; kt < 8; kt++) {
            int w = kt & 3;
            bf8v a0 = *(const bf8v*)(hid_s + col * 264 + kt * 32 + quad * 8);
            bf8v a1 = *(const bf8v*)(hid_s + (16 + col) * 264 + kt * 32 + quad * 8);
#pragma unroll
            for (int t = 0; t < 2; t++) {
                acc[0][t] = __builtin_amdgcn_mfma_f32_16x16x32_bf16(a0, W2H[w][t], acc[0][t], 0, 0, 0);
                acc[1][t] = __builtin_amdgcn_mfma_f32_16x16x32_bf16(a1, W2H[w][t], acc[1][t], 0, 0, 0);
            }
        }
#pragma unroll
        for (int kt = 0; kt < 4; kt++) {
            bf8v a0 = *(const bf8v*)(hid_s + col * 264 + kt * 32 + quad * 8);
            bf8v a1 = *(const bf8v*)(hid_s + (16 + col) * 264 + kt * 32 + quad * 8);
#pragma unroll
            for (int t = 0; t < 2; t++) {
                acc[0][t] = __builtin_amdgcn_mfma_f32_16x16x32_bf16(a0, W2L[kt][t], acc[0][t], 0, 0, 0);
                acc[1][t] = __builtin_amdgcn_mfma_f32_16x16x32_bf16(a1, W2L[kt][t], acc[1][t], 0, 0, 0);
            }
        }
        __syncthreads();
#pragma unroll
        for (int mt = 0; mt < 2; mt++)
#pragma unroll
            for (int t = 0; t < 2; t++) {
                const int nc = (2 * wave + t) * 16 + col;
#pragma unroll
                for (int r = 0; r < 4; r++)
                    hid_s[(mt * 16 + quad * 4 + r) * 264 + nc] = f2bf(acc[mt][t][r] + bias2[t]);
            }
        __syncthreads();
#pragma unroll
        for (int p = 0; p < 2; p++) {
            int s2 = p * 256 + tid, e = s2 >> 4, c16 = s2 & 15;
            *(uint4*)(el + (size_t)(base + e) * 128 + c16 * 8) =
                *(const uint4*)(hid_s + e * 264 + c16 * 8);
        }
    }
}

// ---------------- MFMA edge processor step (CSR order; gathers fp32 nl with inline cvt) ----------------

__global__ __launch_bounds__(256) void k_edge_step(
    unsigned short* __restrict__ el, const float* __restrict__ nl,
    const unsigned short* __restrict__ snd, const unsigned short* __restrict__ rcv,
    const unsigned short* __restrict__ w1f, const float* __restrict__ b1,
    const unsigned short* __restrict__ w2f, const float* __restrict__ b2) {
    __shared__ __align__(16) unsigned short inl_s[32 * 392];
    __shared__ __align__(16) unsigned short hid_s[32 * 136];
    __shared__ int s_idx[64];
    const int tid = threadIdx.x;
    const int wave = tid >> 6, lane = tid & 63;
    const int col = lane & 15, quad = lane >> 4;

    bf8v W1[12][2], W2[4][2];
#pragma unroll
    for (int kt = 0; kt < 12; kt++)
#pragma unroll
        for (int t = 0; t < 2; t++)
            W1[kt][t] = *(const bf8v*)(w1f + ((size_t)(kt * 8 + 2 * wave + t) * 64 + lane) * 8);
#pragma unroll
    for (int kt = 0; kt < 4; kt++)
#pragma unroll
        for (int t = 0; t < 2; t++)
            W2[kt][t] = *(const bf8v*)(w2f + ((size_t)(kt * 8 + 2 * wave + t) * 64 + lane) * 8);
    float bias1[2], bias2[2];
#pragma unroll
    for (int t = 0; t < 2; t++) {
        bias1[t] = b1[(2 * wave + t) * 16 + col];
        bias2[t] = b2[(2 * wave + t) * 16 + col];
    }

    for (int it = 0; it < 4; it++) {
        const int base = blockIdx.x * 128 + it * 32;
        if (tid < 64) s_idx[tid] = (tid < 32) ? (int)snd[base + tid] : (int)rcv[base + tid - 32];
        __syncthreads();
#pragma unroll
        for (int p = 0; p < 2; p++) {
            int s = p * 256 + tid, e = s >> 4, c16 = s & 15;
            *(uint4*)(inl_s + e * 392 + c16 * 8) =
                *(const uint4*)(el + (size_t)(base + e) * 128 + c16 * 8);
            {
                const float* src = nl + (size_t)s_idx[e] * 128 + c16 * 8;
                float4 v0 = *(const float4*)src, v1 = *(const float4*)(src + 4);
                u16x8 o;
                o[0] = f2bf(v0.x); o[1] = f2bf(v0.y); o[2] = f2bf(v0.z); o[3] = f2bf(v0.w);
                o[4] = f2bf(v1.x); o[5] = f2bf(v1.y); o[6] = f2bf(v1.z); o[7] = f2bf(v1.w);
                *(u16x8*)(inl_s + e * 392 + 128 + c16 * 8) = o;
            }
            {
                const float* src = nl + (size_t)s_idx[32 + e] * 128 + c16 * 8;
                float4 v0 = *(const float4*)src, v1 = *(const float4*)(src + 4);
                u16x8 o;
                o[0] = f2bf(v0.x); o[1] = f2bf(v0.y); o[2] = f2bf(v0.z); o[3] = f2bf(v0.w);
                o[4] = f2bf(v1.x); o[5] = f2bf(v1.y); o[6] = f2bf(v1.z); o[7] = f2bf(v1.w);
                *(u16x8*)(inl_s + e * 392 + 256 + c16 * 8) = o;
            }
        }
        __syncthreads();

        f4v acc[2][2];
#pragma unroll
        for (int mt = 0; mt < 2; mt++)
#pragma unroll
            for (int t = 0; t < 2; t++) acc[mt][t] = (f4v){0.f, 0.f, 0.f, 0.f};
#pragma unroll
        for (int kt = 0; kt < 12; kt++) {
            bf8v a0 = *(const bf8v*)(inl_s + col * 392 + kt * 32 + quad * 8);
            bf8v a1 = *(const bf8v*)(inl_s + (16 + col) * 392 + kt * 32 + quad * 8);
            acc[0][0] = __builtin_amdgcn_mfma_f32_16x16x32_bf16(a0, W1[kt][0], acc[0][0], 0, 0, 0);
            acc[0][1] = __builtin_amdgcn_mfma_f32_16x16x32_bf16(a0, W1[kt][1], acc[0][1], 0, 0, 0);
            acc[1][0] = __builtin_amdgcn_mfma_f32_16x16x32_bf16(a1, W1[kt][0], acc[1][0], 0, 0, 0);
            acc[1][1] = __builtin_amdgcn_mfma_f32_16x16x32_bf16(a1, W1[kt][1], acc[1][1], 0, 0, 0);
        }
#pragma unroll
        for (int mt = 0; mt < 2; mt++)
#pragma unroll
            for (int t = 0; t < 2; t++) {
                const int nc = (2 * wave + t) * 16 + col;
#pragma unroll
                for (int r = 0; r < 4; r++) {
                    float v = fmaxf(acc[mt][t][r] + bias1[t], 0.f);
                    hid_s[(mt * 16 + quad * 4 + r) * 136 + nc] = f2bf(v);
                }
            }
        __syncthreads();

#pragma unroll
        for (int mt = 0; mt < 2; mt++)
#pragma unroll
            for (int t = 0; t < 2; t++) acc[mt][t] = (f4v){0.f, 0.f, 0.f, 0.f};
#pragma unroll
        for (int kt = 0; kt < 4; kt++) {
            bf8v a0 = *(const bf8v*)(hid_s + col * 136 + kt * 32 + quad * 8);
            bf8v a1 = *(const bf8v*)(hid_s + (16 + col) * 136 + kt * 32 + quad * 8);
            acc[0][0] = __builtin_amdgcn_mfma_f32_16x16x32_bf16(a0, W2[kt][0], acc[0][0], 0, 0, 0);
            acc[0][1] = __builtin_amdgcn_mfma_f32_16x16x32_bf16(a0, W2[kt][1], acc[0][1], 0, 0, 0);
            acc[1][0] = __builtin_amdgcn_mfma_f32_16x16x32_bf16(a1, W2[kt][0], acc[1][0], 0, 0, 0);
            acc[1][1] = __builtin_amdgcn_mfma_f32_16x16x32_bf16(a1, W2[kt][1], acc[1][1], 0, 0, 0);
        }
        __syncthreads();
#pragma unroll
        for (int mt = 0; mt < 2; mt++)
#pragma unroll
            for (int t = 0; t < 2; t++) {
                const int nc = (2 * wave + t) * 16 + col;
#pragma unroll
                for (int r = 0; r < 4; r++) {
                    const int row = mt * 16 + quad * 4 + r;
                    float v = acc[mt][t][r] + bias2[t] + bflo((unsigned int)inl_s[row * 392 + nc]);
                    hid_s[row * 136 + nc] = f2bf(v);
                }
            }
        __syncthreads();
#pragma unroll
        for (int p = 0; p < 2; p++) {
            int s = p * 256 + tid, e = s >> 4, c16 = s & 15;
            *(uint4*)(el + (size_t)(base + e) * 128 + c16 * 8) =
                *(const uint4*)(hid_s + e * 136 + c16 * 8);
        }
    }
}

// ---------------- node step: [nl_hi|nl_lo|agg_hi] (K=384) -> 128 -> 128, residual, fp32 out ----------------
// 64 nodes/block (2 tiles of 32), grid 782. agg precomputed bf16 by k_agg.

__global__ __launch_bounds__(256) void k_node_step_s(
    float* __restrict__ nl, const unsigned short* __restrict__ agg,
    const unsigned short* __restrict__ w1h, const unsigned short* __restrict__ w1l,
    const float* __restrict__ b1,
    const unsigned short* __restrict__ w2h, const unsigned short* __restrict__ w2l,
    const float* __restrict__ b2) {
    __shared__ __align__(16) unsigned short a_s[32 * 392];
    __shared__ __align__(16) unsigned short hid_s[32 * 264];
    const int tid = threadIdx.x, wave = tid >> 6, lane = tid & 63;
    const int col = lane & 15, quad = lane >> 4;
    bf8v W1H[8][2], W1L[8][2], W2H[4][2], W2L[4][2];
#pragma unroll
    for (int kt = 0; kt < 8; kt++)
#pragma unroll
        for (int t = 0; t < 2; t++) {
            W1H[kt][t] = *(const bf8v*)(w1h + ((size_t)(kt * 8 + 2 * wave + t) * 64 + lane) * 8);
            W1L[kt][t] = *(const bf8v*)(w1l + ((size_t)(kt * 8 + 2 * wave + t) * 64 + lane) * 8);
        }
#pragma unroll
    for (int kt = 0; kt < 4; kt++)
#pragma unroll
        for (int t = 0; t < 2; t++) {
            W2H[kt][t] = *(const bf8v*)(w2h + ((size_t)(kt * 8 + 2 * wave + t) * 64 + lane) * 8);
            W2L[kt][t] = *(const bf8v*)(w2l + ((size_t)(kt * 8 + 2 * wave + t) * 64 + lane) * 8);
        }
    float bias1[2], bias2[2];
#pragma unroll
    for (int t = 0; t < 2; t++) {
        bias1[t] = b1[(2 * wave + t) * 16 + col];
        bias2[t] = b2[(2 * wave + t) * 16 + col];
    }
    for (int it = 0; it < 2; it++) {
        const int base = blockIdx.x * 64 + it * 32;
        if (base >= NN) break;
        __syncthreads();  // prev-iter a_s/hid_s reads done
        // stage nl fp32 -> hi/lo  (a_s[:,0:128] hi, [128:256] lo)
#pragma unroll
        for (int p = 0; p < 4; p++) {
            int s2 = p * 256 + tid, e = s2 >> 5, c4 = s2 & 31;
            int n = base + e; if (n > NN - 1) n = NN - 1;
            float4 v = *(const float4*)(nl + (size_t)n * 128 + c4 * 4);
            ushort4 hi, lo;
            hi.x = f2bf(v.x); lo.x = f2bf(v.x - bflo(hi.x));
            hi.y = f2bf(v.y); lo.y = f2bf(v.y - bflo(hi.y));
            hi.z = f2bf(v.z); lo.z = f2bf(v.z - bflo(hi.z));
            hi.w = f2bf(v.w); lo.w = f2bf(v.w - bflo(hi.w));
            *(ushort4*)(a_s + e * 392 + c4 * 4) = hi;
            *(ushort4*)(a_s + e * 392 + 128 + c4 * 4) = lo;
        }
        // stage agg bf16 (a_s[:,256:384])
#pragma unroll
        for (int p = 0; p < 2; p++) {
            int s2 = p * 256 + tid, e = s2 >> 4, c16 = s2 & 15;
            int n = base + e; if (n > NN - 1) n = NN - 1;
            *(uint4*)(a_s + e * 392 + 256 + c16 * 8) =
                *(const uint4*)(agg + (size_t)n * 128 + c16 * 8);
        }
        __syncthreads();

        f4v acc[2][2];
#pragma unroll
        for (int mt = 0; mt < 2; mt++)
#pragma unroll
            for (int t = 0; t < 2; t++) acc[mt][t] = (f4v){0.f, 0.f, 0.f, 0.f};
        // layer1: nl_hi+nl_lo vs W1H[0..3], agg_hi vs W1H[4..7], nl_hi vs W1L[0..3], agg_hi vs W1L[4..7]
#pragma unroll
        for (int kt = 0; kt < 8; kt++) {
            bf8v a0 = *(const bf8v*)(a_s + col * 392 + kt * 32 + quad * 8);
            bf8v a1 = *(const bf8v*)(a_s + (16 + col) * 392 + kt * 32 + quad * 8);
#pragma unroll
            for (int t = 0; t < 2; t++) {
                acc[0][t] = __builtin_amdgcn_mfma_f32_16x16x32_bf16(a0, W1H[kt & 3][t], acc[0][t], 0, 0, 0);
                acc[1][t] = __builtin_amdgcn_mfma_f32_16x16x32_bf16(a1, W1H[kt & 3][t], acc[1][t], 0, 0, 0);
            }
        }
#pragma unroll
        for (int kt = 0; kt < 4; kt++) {
            bf8v a0 = *(const bf8v*)(a_s + col * 392 + 256 + kt * 32 + quad * 8);
            bf8v a1 = *(const bf8v*)(a_s + (16 + col) * 392 + 256 + kt * 32 + quad * 8);
#pragma unroll
            for (int t = 0; t < 2; t++) {
                acc[0][t] = __builtin_amdgcn_mfma_f32_16x16x32_bf16(a0, W1H[4 + kt][t], acc[0][t], 0, 0, 0);
                acc[1][t] = __builtin_amdgcn_mfma_f32_16x16x32_bf16(a1, W1H[4 + kt][t], acc[1][t], 0, 0, 0);
            }
        }
#pragma unroll
        for (int kt = 0; kt < 4; kt++) {
            bf8v a0 = *(const bf8v*)(a_s + col * 392 + kt * 32 + quad * 8);
            bf8v a1 = *(const bf8v*)(a_s + (16 + col) * 392 + kt * 32 + quad * 8);
#pragma unroll
            for (int t = 0; t < 2; t++) {
                acc[0][t] = __builtin_amdgcn_mfma_f32_16x16x32_bf16(a0, W1L[kt][t], acc[0][t], 0, 0, 0);
                acc[1][t] = __builtin_amdgcn_mfma_f32_16x16x32_bf16(a1, W1L[kt][t], acc[1][t], 0, 0, 0);
            }
        }
#pragma unroll
        for (int kt = 0; kt < 4; kt++) {
            bf8v a0 = *(const bf8v*)(a_s + col * 392 + 256 + kt * 32 + quad * 8);
            bf8v a1 = *(const bf8v*)(a_s + (16 + col) * 392 + 256 + kt * 32 + quad * 8);
#pragma unroll
            for (int t = 0; t < 2; t++) {
                acc[0][t] = __builtin_amdgcn_mfma_f32_16x16x32_bf16(a0, W1L[4 + kt][t], acc[0][t], 0, 0, 0);
                acc[1][t] = __builtin_amdgcn_mfma_f32_16x16x32_bf16(a1, W1L[4 + kt][t], acc[1][t], 0, 0, 0);
            }
        }
#pragma unroll
        for (int mt = 0; mt < 2; mt++)
#pragma unroll
            for (int t = 0; t < 2; t++) {
                const int nc = (2 * wave + t) * 16 + col;
#pragma unroll
                for (int r = 0; r < 4; r++) {
                    float h = fmaxf(acc[mt][t][r] + bias1[t], 0.f);
                    unsigned short hh = f2bf(h);
                    hid_s[(mt * 16 + quad * 4 + r) * 264 + nc] = hh;
                    hid_s[(mt * 16 + quad * 4 + r) * 264 + 128 + nc] = f2bf(h - bflo(hh));
                }
            }
        __syncthreads();
#pragma unroll
        for (int mt = 0; mt < 2; mt++)
#pragma unroll
            for (int t = 0; t < 2; t++) acc[mt][t] = (f4v){0.f, 0.f, 0.f, 0.f};
#pragma unroll
        for (int kt = 0; kt < 8; kt++) {
            int w = kt & 3;
            bf8v a0 = *(const bf8v*)(hid_s + col * 264 + kt * 32 + quad * 8);
            bf8v a1 = *(const bf8v*)(hid_s + (16 + col) * 264 + kt * 32 + quad * 8);
#pragma unroll
            for (int t = 0; t < 2; t++) {
                acc[0][t] = __builtin_amdgcn_mfma_f32_16x16x32_bf16(a0, W2H[w][t], acc[0][t], 0, 0, 0);
                acc[1][t] = __builtin_amdgcn_mfma_f32_16x16x32_bf16(a1, W2H[w][t], acc[1][t], 0, 0, 0);
            }
        }
#pragma unroll
        for (int kt = 0; kt < 4; kt++) {
            bf8v a0 = *(const bf8v*)(hid_s + col * 264 + kt * 32 + quad * 8);
            bf8v a1 = *(const bf8v*)(hid_s + (16 + col) * 264 + kt * 32 + quad * 8);
#pragma unroll
            for (int t = 0; t < 2; t++) {
                acc[0][t] = __builtin_amdgcn_mfma_f32_16x16x32_bf16(a0, W2L[kt][t], acc[0][t], 0, 0, 0);
                acc[1][t] = __builtin_amdgcn_mfma_f32_16x16x32_bf16(a1, W2L[kt][t], acc[1][t], 0, 0, 0);
            }
        }
        // epilogue: residual + store fp32 nl directly (no LDS round-trip needed)
#pragma unroll
        for (int mt = 0; mt < 2; mt++)
#pragma unroll
            for (int t = 0; t < 2; t++) {
                const int nc = (2 * wave + t) * 16 + col;
#pragma unroll
                for (int r = 0; r < 4; r++) {
                    const int row = mt * 16 + quad * 4 + r;
                    int n = base + row;
                    if (n < NN) {
                        float v = acc[mt][t][r] + bias2[t] + nl[(size_t)n * 128 + nc];
                        nl[(size_t)n * 128 + nc] = v;
                    }
                }
            }
    }
}

// ---------------- decoder: 128 -> 128 -> 3 (fp32 VALU, reads fp32 nl) ----------------

__global__ __launch_bounds__(128) void k_decode(
    const float* __restrict__ nl,
    const float* __restrict__ w1, const float* __restrict__ b1,
    const float* __restrict__ w2, const float* __restrict__ b2,
    float* __restrict__ out) {
    __shared__ float inl[16][128];
    __shared__ float hid[16][128];
    int j = threadIdx.x;
    int base = blockIdx.x * 16;
    for (int e = 0; e < 16; e++) inl[e][j] = nl[(size_t)(base + e) * 128 + j];
    __syncthreads();
    float acc[16];
#pragma unroll
    for (int e = 0; e < 16; e++) acc[e] = b1[j];
    for (int kc = 0; kc < 16; kc++) {
        float w[8];
#pragma unroll
        for (int t = 0; t < 8; t++) w[t] = w1[(kc * 8 + t) * 128 + j];
#pragma unroll
        for (int e = 0; e < 16; e++) {
            float4 h0 = *(const float4*)&inl[e][kc * 8];
            float4 h1 = *(const float4*)&inl[e][kc * 8 + 4];
            acc[e] = fmaf(h0.x, w[0], acc[e]); acc[e] = fmaf(h0.y, w[1], acc[e]);
            acc[e] = fmaf(h0.z, w[2], acc[e]); acc[e] = fmaf(h0.w, w[3], acc[e]);
            acc[e] = fmaf(h1.x, w[4], acc[e]); acc[e] = fmaf(h1.y, w[5], acc[e]);
            acc[e] = fmaf(h1.z, w[6], acc[e]); acc[e] = fmaf(h1.w, w[7], acc[e]);
        }
    }
#pragma unroll
    for (int e = 0; e < 16; e++) hid[e][j] = fmaxf(acc[e], 0.f);
    __syncthreads();
    if (j < 48) {
        int e = j / 3, ch = j - 3 * (j / 3);
        float s = b2[ch];
        for (int k = 0; k < 128; k++) s = fmaf(hid[e][k], w2[k * 3 + ch], s);
        out[(size_t)(base + e) * 3 + ch] = s;
    }
}

// ---------------- launch ----------------

extern "C" void kernel_launch(void* const* d_in, const int* in_sizes, int n_in,
                              void* d_out, int out_size, void* d_ws, size_t ws_size,
                              hipStream_t stream) {
    (void)in_sizes; (void)n_in; (void)out_size; (void)ws_size;
    const float* pos   = (const float*)d_in[0];
    const float* vel   = (const float*)d_in[1];
    const int*   rid   = (const int*)d_in[2];
    const int*   snd   = (const int*)d_in[3];
    const int*   rcv   = (const int*)d_in[4];
    const float* remb  = (const float*)d_in[5];
    const float* ne_w1 = (const float*)d_in[6];
    const float* ne_b1 = (const float*)d_in[7];
    const float* ne_w2 = (const float*)d_in[8];
    const float* ne_b2 = (const float*)d_in[9];
    const float* ee_w1 = (const float*)d_in[10];
    const float* ee_b1 = (const float*)d_in[11];
    const float* ee_w2 = (const float*)d_in[12];
    const float* ee_b2 = (const float*)d_in[13];
    const float* pe_w1 = (const float*)d_in[14];
    const float* pe_b1 = (const float*)d_in[15];
    const float* pe_w2 = (const float*)d_in[16];
    const float* pe_b2 = (const float*)d_in[17];
    const float* pn_w1 = (const float*)d_in[18];
    const float* pn_b1 = (const float*)d_in[19];
    const float* pn_w2 = (const float*)d_in[20];
    const float* pn_b2 = (const float*)d_in[21];
    const float* de_w1 = (const float*)d_in[22];
    const float* de_b1 = (const float*)d_in[23];
    const float* de_w2 = (const float*)d_in[24];
    const float* de_b2 = (const float*)d_in[25];
    float* out = (float*)d_out;

    // workspace carve (~250.6e6 B — under the 256.2e6 proven available in round 1)
    char* p = (char*)d_ws;
    auto carve = [&](size_t bytes) { void* q = (void*)p; p += (bytes + 15) & ~(size_t)15; return q; };
    unsigned short* el    = (unsigned short*)carve((size_t)NE * LDIM * 2);   // 204.8e6, CSR order
    float*          nl    = (float*)carve((size_t)NN * LDIM * 4);            // 25.6e6
    unsigned short* agg   = (unsigned short*)carve((size_t)NN * LDIM * 2);   // 12.8e6 (bf16)
    unsigned short* w1f_e = (unsigned short*)carve((size_t)NSTEPS * 12 * 8 * 512 * 2);
    unsigned short* w2f_e = (unsigned short*)carve((size_t)NSTEPS * 4 * 8 * 512 * 2);
    unsigned short* w1h_n = (unsigned short*)carve((size_t)NSTEPS * 8 * 8 * 512 * 2);
    unsigned short* w1l_n = (unsigned short*)carve((size_t)NSTEPS * 8 * 8 * 512 * 2);
    unsigned short* w2h_n = (unsigned short*)carve((size_t)NSTEPS * 4 * 8 * 512 * 2);
    unsigned short* w2l_n = (unsigned short*)carve((size_t)NSTEPS * 4 * 8 * 512 * 2);
    unsigned short* eew1h = (unsigned short*)carve((size_t)1 * 8 * 512 * 2);
    unsigned short* eew1l = (unsigned short*)carve((size_t)1 * 8 * 512 * 2);
    unsigned short* eew2h = (unsigned short*)carve((size_t)4 * 8 * 512 * 2);
    unsigned short* eew2l = (unsigned short*)carve((size_t)4 * 8 * 512 * 2);
    unsigned short* new1h = (unsigned short*)carve((size_t)1 * 8 * 512 * 2);
    unsigned short* new1l = (unsigned short*)carve((size_t)1 * 8 * 512 * 2);
    unsigned short* new2h = (unsigned short*)carve((size_t)4 * 8 * 512 * 2);
    unsigned short* new2l = (unsigned short*)carve((size_t)4 * 8 * 512 * 2);
    unsigned short* snd_p = (unsigned short*)carve((size_t)NE * 2);          // 1.6e6
    unsigned short* rcv_p = (unsigned short*)carve((size_t)NE * 2);          // 1.6e6
    int*            rs    = (int*)carve((size_t)(NN + 1) * 4);
    int*            cnt   = (int*)carve((size_t)NN * 4);
    int*            cur   = (int*)carve((size_t)NN * 4);
    float*          degf  = (float*)carve((size_t)NN * 4);
    float*          csum  = (float*)carve(16);

    hipMemsetAsync(cnt, 0, (size_t)NN * 4, stream);
    hipMemsetAsync(csum, 0, 16, stream);
    k_hist<<<NE / 256, 256, 0, stream>>>(rcv, cnt);
    k_scan<<<1, 1024, 0, stream>>>(cnt, rs, cur, degf);
    k_center<<<64, 256, 0, stream>>>(pos, csum);
    k_scatter<<<NE / 256, 256, 0, stream>>>(snd, rcv, cur, snd_p, rcv_p);
    k_prep_w<<<NSTEPS * 12 * 8, 64, 0, stream>>>(pe_w1, w1f_e, 12, 384, 0);
    k_prep_w<<<NSTEPS * 4 * 8, 64, 0, stream>>>(pe_w2, w2f_e, 4, 128, 0);
    k_prep_w<<<NSTEPS * 8 * 8, 64, 0, stream>>>(pn_w1, w1h_n, 8, 256, 0);
    k_prep_w<<<NSTEPS * 8 * 8, 64, 0, stream>>>(pn_w1, w1l_n, 8, 256, 1);
    k_prep_w<<<NSTEPS * 4 * 8, 64, 0, stream>>>(pn_w2, w2h_n, 4, 128, 0);
    k_prep_w<<<NSTEPS * 4 * 8, 64, 0, stream>>>(pn_w2, w2l_n, 4, 128, 1);
    k_prep_w<<<8, 64, 0, stream>>>(ee_w1, eew1h, 1, 9, 0);
    k_prep_w<<<8, 64, 0, stream>>>(ee_w1, eew1l, 1, 9, 1);
    k_prep_w<<<4 * 8, 64, 0, stream>>>(ee_w2, eew2h, 4, 128, 0);
    k_prep_w<<<4 * 8, 64, 0, stream>>>(ee_w2, eew2l, 4, 128, 1);
    k_prep_w<<<8, 64, 0, stream>>>(ne_w1, new1h, 1, 23, 0);
    k_prep_w<<<8, 64, 0, stream>>>(ne_w1, new1l, 1, 23, 1);
    k_prep_w<<<4 * 8, 64, 0, stream>>>(ne_w2, new2h, 4, 128, 0);
    k_prep_w<<<4 * 8, 64, 0, stream>>>(ne_w2, new2l, 4, 128, 1);

    k_node_enc_m<<<(NN + 127) / 128, 256, 0, stream>>>(pos, vel, rid, remb, degf, csum,
                                                       new1h, new1l, ne_b1, new2h, new2l, ne_b2, nl);
    k_edge_enc_m<<<NE / 128, 256, 0, stream>>>(pos, vel, rid, snd_p, rcv_p,
                                               eew1h, eew1l, ee_b1, eew2h, eew2l, ee_b2, el);
    for (int i = 0; i < NSTEPS; i++) {
        k_edge_step<<<NE / 128, 256, 0, stream>>>(el, nl, snd_p, rcv_p,
            w1f_e + (size_t)i * 12 * 8 * 512, pe_b1 + i * 128,
            w2f_e + (size_t)i * 4 * 8 * 512, pe_b2 + i * 128);
        k_agg<<<(NN + 3) / 4, 256, 0, stream>>>(el, rs, agg);
        k_node_step_s<<<(NN + 63) / 64, 256, 0, stream>>>(nl, agg,
            w1h_n + (size_t)i * 8 * 8 * 512, w1l_n + (size_t)i * 8 * 8 * 512, pn_b1 + i * 128,
            w2h_n + (size_t)i * 4 * 8 * 512, w2l_n + (size_t)i * 4 * 8 * 512, pn_b2 + i * 128);
    }
    k_decode<<<NN / 16, 128, 0, stream>>>(nl, de_w1, de_b1, de_w2, de_b2, out);
}

// Round 9
// 2915.056 us; speedup vs baseline: 1.5884x; 1.0099x over previous
//
#include <hip/hip_runtime.h>
#include <hip/hip_bf16.h>

#define NN 50000
#define NE 800000
#define LDIM 128
#define NSTEPS 10

typedef __hip_bfloat16 bf16;
typedef __bf16 bf8v __attribute__((ext_vector_type(8)));
typedef float f4v __attribute__((ext_vector_type(4)));
typedef unsigned short u16x8 __attribute__((ext_vector_type(8)));

__device__ inline float bflo(unsigned int u) {
    union { unsigned int i; float f; } x; x.i = u << 16; return x.f;
}
__device__ inline float bfhi(unsigned int u) {
    union { unsigned int i; float f; } x; x.i = u & 0xffff0000u; return x.f;
}
__device__ inline unsigned short f2bf(float f) {
    __hip_bfloat16 h = __float2bfloat16(f);
    unsigned short u; __builtin_memcpy(&u, &h, 2); return u;
}

// ---------------- CSR build: histogram, scan, scatter (ushort permuted endpoints) ----------------

__global__ void k_hist(const int* __restrict__ rcv, int* __restrict__ cnt) {
    int i = blockIdx.x * 256 + threadIdx.x;
    if (i < NE) atomicAdd(&cnt[rcv[i]], 1);
}

__global__ __launch_bounds__(1024) void k_scan(
    const int* __restrict__ cnt, int* __restrict__ row_start,
    int* __restrict__ cur, float* __restrict__ degf) {
    __shared__ int part[1024];
    const int t = threadIdx.x;
    const int CH = (NN + 1023) / 1024;  // 49
    int b0 = t * CH, b1 = b0 + CH; if (b1 > NN) b1 = NN; if (b0 > NN) b0 = NN;
    int s = 0;
    for (int i = b0; i < b1; i++) s += cnt[i];
    part[t] = s;
    __syncthreads();
    for (int off = 1; off < 1024; off <<= 1) {
        int v = (t >= off) ? part[t - off] : 0;
        __syncthreads();
        part[t] += v;
        __syncthreads();
    }
    int run = part[t] - s;  // exclusive prefix
    for (int i = b0; i < b1; i++) {
        row_start[i] = run; cur[i] = run; degf[i] = (float)cnt[i];
        run += cnt[i];
    }
    if (t == 1023) row_start[NN] = part[1023];
}

__global__ void k_scatter(const int* __restrict__ snd, const int* __restrict__ rcv,
                          int* __restrict__ cur,
                          unsigned short* __restrict__ snd_p, unsigned short* __restrict__ rcv_p) {
    int i = blockIdx.x * 256 + threadIdx.x;
    if (i < NE) {
        int r = rcv[i];
        int p = atomicAdd(&cur[r], 1);
        snd_p[p] = (unsigned short)snd[i];
        rcv_p[p] = (unsigned short)r;
    }
}

__global__ void k_center(const float* __restrict__ pos, float* __restrict__ csum) {
    __shared__ float s[3][256];
    float a = 0.f, b = 0.f, c = 0.f;
    for (int i = blockIdx.x * 256 + threadIdx.x; i < NN; i += gridDim.x * 256) {
        a += pos[3 * i]; b += pos[3 * i + 1]; c += pos[3 * i + 2];
    }
    int t = threadIdx.x;
    s[0][t] = a; s[1][t] = b; s[2][t] = c;
    __syncthreads();
    for (int off = 128; off > 0; off >>= 1) {
        if (t < off) {
            s[0][t] += s[0][t + off];
            s[1][t] += s[1][t + off];
            s[2][t] += s[2][t + off];
        }
        __syncthreads();
    }
    if (t == 0) {
        atomicAdd(&csum[0], s[0][0]);
        atomicAdd(&csum[1], s[1][0]);
        atomicAdd(&csum[2], s[2][0]);
    }
}

// ---------------- weight prep: fp32 -> bf16 B-frag order; lo=1 emits bf16(x - bf16(x)) ----------------

__global__ void k_prep_w(const float* __restrict__ w, unsigned short* __restrict__ wf,
                         int KT, int Ksrc, int lo) {
    int b = blockIdx.x;
    int s = b / (KT * 8), rem = b % (KT * 8);
    int kt = rem / 8, nt = rem % 8;
    int lane = threadIdx.x, col = lane & 15, quad = lane >> 4;
    const float* W = w + (size_t)s * Ksrc * 128;
    u16x8 o;
#pragma unroll
    for (int jj = 0; jj < 8; jj++) {
        int k = kt * 32 + quad * 8 + jj;
        float x = (k < Ksrc) ? W[(size_t)k * 128 + nt * 16 + col] : 0.f;
        unsigned short h = f2bf(x);
        if (lo) h = f2bf(x - bflo(h));
        o[jj] = h;
    }
    *(u16x8*)(wf + (((size_t)b) * 64 + lane) * 8) = o;
}

// ---------------- CSR aggregation: streaming reduction el (CSR order) -> bf16 agg ----------------

__global__ __launch_bounds__(256) void k_agg(
    const unsigned short* __restrict__ el, const int* __restrict__ row_start,
    unsigned short* __restrict__ agg) {
    const int wave = threadIdx.x >> 6, lane = threadIdx.x & 63;
    const int n = blockIdx.x * 4 + wave;
    if (n >= NN) return;
    const int sub = lane >> 4, c16 = lane & 15;
    const int st = row_start[n], en = row_start[n + 1];
    float s[8];
#pragma unroll
    for (int k = 0; k < 8; k++) s[k] = 0.f;
    for (int q = st + sub; q < en; q += 4) {
        uint4 v = *(const uint4*)(el + (size_t)q * 128 + c16 * 8);
        s[0] += bflo(v.x); s[1] += bfhi(v.x);
        s[2] += bflo(v.y); s[3] += bfhi(v.y);
        s[4] += bflo(v.z); s[5] += bfhi(v.z);
        s[6] += bflo(v.w); s[7] += bfhi(v.w);
    }
#pragma unroll
    for (int k = 0; k < 8; k++) {
        s[k] += __shfl_xor(s[k], 16);
        s[k] += __shfl_xor(s[k], 32);
    }
    if (sub == 0) {
        u16x8 o;
#pragma unroll
        for (int k = 0; k < 8; k++) o[k] = f2bf(s[k]);
        *(u16x8*)(agg + (size_t)n * 128 + c16 * 8) = o;
    }
}

// ---------------- MFMA node encoder (split-precision): feat(23 pad 32, hi|lo) -> 128 -> 128 ----------------
// Output: node latent as bf16 hi/lo pair (nlh, nll).

__global__ __launch_bounds__(256) void k_node_enc_m(
    const float* __restrict__ pos, const float* __restrict__ vel,
    const int* __restrict__ rid, const float* __restrict__ remb,
    const float* __restrict__ degf, const float* __restrict__ csum,
    const unsigned short* __restrict__ w1h, const unsigned short* __restrict__ w1l,
    const float* __restrict__ b1,
    const unsigned short* __restrict__ w2h, const unsigned short* __restrict__ w2l,
    const float* __restrict__ b2,
    unsigned short* __restrict__ nlh, unsigned short* __restrict__ nll) {
    __shared__ __align__(16) unsigned short feat_s[32 * 72];   // [hi(32)|lo(32)|pad]
    __shared__ __align__(16) unsigned short hid_s[32 * 264];   // [hi(128)|lo(128)|pad]
    const int tid = threadIdx.x, wave = tid >> 6, lane = tid & 63;
    const int col = lane & 15, quad = lane >> 4;
    bf8v W1H[2], W1L[2], W2H[4][2], W2L[4][2];
#pragma unroll
    for (int t = 0; t < 2; t++) {
        W1H[t] = *(const bf8v*)(w1h + ((size_t)(2 * wave + t) * 64 + lane) * 8);
        W1L[t] = *(const bf8v*)(w1l + ((size_t)(2 * wave + t) * 64 + lane) * 8);
    }
#pragma unroll
    for (int kt = 0; kt < 4; kt++)
#pragma unroll
        for (int t = 0; t < 2; t++) {
            W2H[kt][t] = *(const bf8v*)(w2h + ((size_t)(kt * 8 + 2 * wave + t) * 64 + lane) * 8);
            W2L[kt][t] = *(const bf8v*)(w2l + ((size_t)(kt * 8 + 2 * wave + t) * 64 + lane) * 8);
        }
    float bias1[2], bias2[2];
#pragma unroll
    for (int t = 0; t < 2; t++) {
        bias1[t] = b1[(2 * wave + t) * 16 + col];
        bias2[t] = b2[(2 * wave + t) * 16 + col];
    }
    float cx = csum[0] * (1.0f / NN), cy = csum[1] * (1.0f / NN), cz = csum[2] * (1.0f / NN);
    uint4 z = {0u, 0u, 0u, 0u};
    for (int s2 = tid; s2 < 288; s2 += 256) *(uint4*)(feat_s + s2 * 8) = z;  // zero K-pad

    for (int it = 0; it < 4; it++) {
        const int base = blockIdx.x * 128 + it * 32;
        if (base >= NN) break;
        __syncthreads();
        if (tid < 32) {
            int n = base + tid; if (n > NN - 1) n = NN - 1;
            float v[23];
            v[0] = vel[3 * n]; v[1] = vel[3 * n + 1]; v[2] = vel[3 * n + 2];
            v[3] = pos[3 * n] - cx; v[4] = pos[3 * n + 1] - cy; v[5] = pos[3 * n + 2] - cz;
            v[6] = degf[n];
            int rb = rid[n] * 16;
#pragma unroll
            for (int k = 0; k < 16; k++) v[7 + k] = remb[rb + k];
            unsigned short* f = feat_s + tid * 72;
#pragma unroll
            for (int k = 0; k < 23; k++) {
                unsigned short h = f2bf(v[k]);
                f[k] = h; f[32 + k] = f2bf(v[k] - bflo(h));
            }
        }
        __syncthreads();
        f4v acc[2][2];
#pragma unroll
        for (int mt = 0; mt < 2; mt++)
#pragma unroll
            for (int t = 0; t < 2; t++) acc[mt][t] = (f4v){0.f, 0.f, 0.f, 0.f};
        {
            bf8v a0h = *(const bf8v*)(feat_s + col * 72 + quad * 8);
            bf8v a1h = *(const bf8v*)(feat_s + (16 + col) * 72 + quad * 8);
            bf8v a0l = *(const bf8v*)(feat_s + col * 72 + 32 + quad * 8);
            bf8v a1l = *(const bf8v*)(feat_s + (16 + col) * 72 + 32 + quad * 8);
#pragma unroll
            for (int t = 0; t < 2; t++) {
                acc[0][t] = __builtin_amdgcn_mfma_f32_16x16x32_bf16(a0h, W1H[t], acc[0][t], 0, 0, 0);
                acc[1][t] = __builtin_amdgcn_mfma_f32_16x16x32_bf16(a1h, W1H[t], acc[1][t], 0, 0, 0);
                acc[0][t] = __builtin_amdgcn_mfma_f32_16x16x32_bf16(a0l, W1H[t], acc[0][t], 0, 0, 0);
                acc[1][t] = __builtin_amdgcn_mfma_f32_16x16x32_bf16(a1l, W1H[t], acc[1][t], 0, 0, 0);
                acc[0][t] = __builtin_amdgcn_mfma_f32_16x16x32_bf16(a0h, W1L[t], acc[0][t], 0, 0, 0);
                acc[1][t] = __builtin_amdgcn_mfma_f32_16x16x32_bf16(a1h, W1L[t], acc[1][t], 0, 0, 0);
            }
        }
#pragma unroll
        for (int mt = 0; mt < 2; mt++)
#pragma unroll
            for (int t = 0; t < 2; t++) {
                const int nc = (2 * wave + t) * 16 + col;
#pragma unroll
                for (int r = 0; r < 4; r++) {
                    float h = fmaxf(acc[mt][t][r] + bias1[t], 0.f);
                    unsigned short hh = f2bf(h);
                    hid_s[(mt * 16 + quad * 4 + r) * 264 + nc] = hh;
                    hid_s[(mt * 16 + quad * 4 + r) * 264 + 128 + nc] = f2bf(h - bflo(hh));
                }
            }
        __syncthreads();
#pragma unroll
        for (int mt = 0; mt < 2; mt++)
#pragma unroll
            for (int t = 0; t < 2; t++) acc[mt][t] = (f4v){0.f, 0.f, 0.f, 0.f};
#pragma unroll
        for (int kt = 0; kt < 8; kt++) {
            int w = kt & 3;
            bf8v a0 = *(const bf8v*)(hid_s + col * 264 + kt * 32 + quad * 8);
            bf8v a1 = *(const bf8v*)(hid_s + (16 + col) * 264 + kt * 32 + quad * 8);
#pragma unroll
            for (int t = 0; t < 2; t++) {
                acc[0][t] = __builtin_amdgcn_mfma_f32_16x16x32_bf16(a0, W2H[w][t], acc[0][t], 0, 0, 0);
                acc[1][t] = __builtin_amdgcn_mfma_f32_16x16x32_bf16(a1, W2H[w][t], acc[1][t], 0, 0, 0);
            }
        }
#pragma unroll
        for (int kt = 0; kt < 4; kt++) {
            bf8v a0 = *(const bf8v*)(hid_s + col * 264 + kt * 32 + quad * 8);
            bf8v a1 = *(const bf8v*)(hid_s + (16 + col) * 264 + kt * 32 + quad * 8);
#pragma unroll
            for (int t = 0; t < 2; t++) {
                acc[0][t] = __builtin_amdgcn_mfma_f32_16x16x32_bf16(a0, W2L[kt][t], acc[0][t], 0, 0, 0);
                acc[1][t] = __builtin_amdgcn_mfma_f32_16x16x32_bf16(a1, W2L[kt][t], acc[1][t], 0, 0, 0);
            }
        }
        __syncthreads();  // all hid reads done; overwrite with output hi/lo
#pragma unroll
        for (int mt = 0; mt < 2; mt++)
#pragma unroll
            for (int t = 0; t < 2; t++) {
                const int nc = (2 * wave + t) * 16 + col;
#pragma unroll
                for (int r = 0; r < 4; r++) {
                    const int row = mt * 16 + quad * 4 + r;
                    float v = acc[mt][t][r] + bias2[t];
                    unsigned short hh = f2bf(v);
                    hid_s[row * 264 + nc] = hh;
                    hid_s[row * 264 + 128 + nc] = f2bf(v - bflo(hh));
                }
            }
        __syncthreads();
#pragma unroll
        for (int p = 0; p < 2; p++) {
            int s2 = p * 256 + tid, e = s2 >> 4, c16 = s2 & 15;
            if (base + e < NN) {
                *(uint4*)(nlh + (size_t)(base + e) * 128 + c16 * 8) =
                    *(const uint4*)(hid_s + e * 264 + c16 * 8);
                *(uint4*)(nll + (size_t)(base + e) * 128 + c16 * 8) =
                    *(const uint4*)(hid_s + e * 264 + 128 + c16 * 8);
            }
        }
    }
}

// ---------------- MFMA edge encoder (split-precision): feat(9 pad 32, hi|lo) -> 128 -> 128 ----------------

__global__ __launch_bounds__(256) void k_edge_enc_m(
    const float* __restrict__ pos, const float* __restrict__ vel,
    const int* __restrict__ rid,
    const unsigned short* __restrict__ snd, const unsigned short* __restrict__ rcv,
    const unsigned short* __restrict__ w1h, const unsigned short* __restrict__ w1l,
    const float* __restrict__ b1,
    const unsigned short* __restrict__ w2h, const unsigned short* __restrict__ w2l,
    const float* __restrict__ b2,
    unsigned short* __restrict__ el) {
    __shared__ __align__(16) unsigned short feat_s[32 * 72];
    __shared__ __align__(16) unsigned short hid_s[32 * 264];
    const int tid = threadIdx.x, wave = tid >> 6, lane = tid & 63;
    const int col = lane & 15, quad = lane >> 4;
    bf8v W1H[2], W1L[2], W2H[4][2], W2L[4][2];
#pragma unroll
    for (int t = 0; t < 2; t++) {
        W1H[t] = *(const bf8v*)(w1h + ((size_t)(2 * wave + t) * 64 + lane) * 8);
        W1L[t] = *(const bf8v*)(w1l + ((size_t)(2 * wave + t) * 64 + lane) * 8);
    }
#pragma unroll
    for (int kt = 0; kt < 4; kt++)
#pragma unroll
        for (int t = 0; t < 2; t++) {
            W2H[kt][t] = *(const bf8v*)(w2h + ((size_t)(kt * 8 + 2 * wave + t) * 64 + lane) * 8);
            W2L[kt][t] = *(const bf8v*)(w2l + ((size_t)(kt * 8 + 2 * wave + t) * 64 + lane) * 8);
        }
    float bias1[2], bias2[2];
#pragma unroll
    for (int t = 0; t < 2; t++) {
        bias1[t] = b1[(2 * wave + t) * 16 + col];
        bias2[t] = b2[(2 * wave + t) * 16 + col];
    }
    uint4 z = {0u, 0u, 0u, 0u};
    for (int s2 = tid; s2 < 288; s2 += 256) *(uint4*)(feat_s + s2 * 8) = z;

    for (int it = 0; it < 4; it++) {
        const int base = blockIdx.x * 128 + it * 32;
        __syncthreads();
        if (tid < 32) {
            int e = base + tid;
            int s = snd[e], r = rcv[e];
            float v[9];
            v[0] = pos[3 * s] - pos[3 * r]; v[1] = pos[3 * s + 1] - pos[3 * r + 1]; v[2] = pos[3 * s + 2] - pos[3 * r + 2];
            v[3] = vel[3 * s] - vel[3 * r]; v[4] = vel[3 * s + 1] - vel[3 * r + 1]; v[5] = vel[3 * s + 2] - vel[3 * r + 2];
            float sq = v[0] * v[0] + v[1] * v[1] + v[2] * v[2];
            v[6] = sqrtf(sq); v[7] = sq;
            v[8] = (rid[s] == rid[r]) ? 1.f : 0.f;
            unsigned short* f = feat_s + tid * 72;
#pragma unroll
            for (int k = 0; k < 9; k++) {
                unsigned short h = f2bf(v[k]);
                f[k] = h; f[32 + k] = f2bf(v[k] - bflo(h));
            }
        }
        __syncthreads();
        f4v acc[2][2];
#pragma unroll
        for (int mt = 0; mt < 2; mt++)
#pragma unroll
            for (int t = 0; t < 2; t++) acc[mt][t] = (f4v){0.f, 0.f, 0.f, 0.f};
        {
            bf8v a0h = *(const bf8v*)(feat_s + col * 72 + quad * 8);
            bf8v a1h = *(const bf8v*)(feat_s + (16 + col) * 72 + quad * 8);
            bf8v a0l = *(const bf8v*)(feat_s + col * 72 + 32 + quad * 8);
            bf8v a1l = *(const bf8v*)(feat_s + (16 + col) * 72 + 32 + quad * 8);
#pragma unroll
            for (int t = 0; t < 2; t++) {
                acc[0][t] = __builtin_amdgcn_mfma_f32_16x16x32_bf16(a0h, W1H[t], acc[0][t], 0, 0, 0);
                acc[1][t] = __builtin_amdgcn_mfma_f32_16x16x32_bf16(a1h, W1H[t], acc[1][t], 0, 0, 0);
                acc[0][t] = __builtin_amdgcn_mfma_f32_16x16x32_bf16(a0l, W1H[t], acc[0][t], 0, 0, 0);
                acc[1][t] = __builtin_amdgcn_mfma_f32_16x16x32_bf16(a1l, W1H[t], acc[1][t], 0, 0, 0);
                acc[0][t] = __builtin_amdgcn_mfma_f32_16x16x32_bf16(a0h, W1L[t], acc[0][t], 0, 0, 0);
                acc[1][t] = __builtin_amdgcn_mfma_f32_16x16x32_bf16(a1h, W1L[t], acc[1][t], 0, 0, 0);
            }
        }
#pragma unroll
        for (int mt = 0; mt < 2; mt++)
#pragma unroll
            for (int t = 0; t < 2; t++) {
                const int nc = (2 * wave + t) * 16 + col;
#pragma unroll
                for (int r = 0; r < 4; r++) {
                    float h = fmaxf(acc[mt][t][r] + bias1[t], 0.f);
                    unsigned short hh = f2bf(h);
                    hid_s[(mt * 16 + quad * 4 + r) * 264 + nc] = hh;
                    hid_s[(mt * 16 + quad * 4 + r) * 264 + 128 + nc] = f2bf(h - bflo(hh));
                }
            }
        __syncthreads();
#pragma unroll
        for (int mt = 0; mt < 2; mt++)
#pragma unroll
            for (int t = 0; t < 2; t++) acc[mt][t] = (f4v){0.f, 0.f, 0.f, 0.f};
#pragma unroll
        for (int kt = 0; kt < 8; kt++) {
            int w = kt & 3;
            bf8v a0 = *(const bf8v*)(hid_s + col * 264 + kt * 32 + quad * 8);
            bf8v a1 = *(const bf8v*)(hid_s + (16 + col) * 264 + kt * 32 + quad * 8);
#pragma unroll
            for (int t = 0; t < 2; t++) {
                acc[0][t] = __builtin_amdgcn_mfma_f32_16x16x32_bf16(a0, W2H[w][t], acc[0][t], 0, 0, 0);
                acc[1][t] = __builtin_amdgcn_mfma_f32_16x16x32_bf16(a1, W2H[w][t], acc[1][t], 0, 0, 0);
            }
        }
#pragma unroll
        for (int kt = 0; kt < 4; kt++) {
            bf8v a0 = *(const bf8v*)(hid_s + col * 264 + kt * 32 + quad * 8);
            bf8v a1 = *(const bf8v*)(hid_s + (16 + col) * 264 + kt * 32 + quad * 8);
#pragma unroll
            for (int t = 0; t < 2; t++) {
                acc[0][t] = __builtin_amdgcn_mfma_f32_16x16x32_bf16(a0, W2L[kt][t], acc[0][t], 0, 0, 0);
                acc[1][t] = __builtin_amdgcn_mfma_f32_16x16x32_bf16(a1, W2L[kt][t], acc[1][t], 0, 0, 0);
            }
        }
        __syncthreads();
#pragma unroll
        for (int mt = 0; mt < 2; mt++)
#pragma unroll
            for (int t = 0; t < 2; t++) {
                const int nc = (2 * wave + t) * 16 + col;
#pragma unroll
                for (int r = 0; r < 4; r++)
                    hid_s[(mt * 16 + quad * 4 + r) * 264 + nc] = f2bf(acc[mt][t][r] + bias2[t]);
            }
        __syncthreads();
#pragma unroll
        for (int p = 0; p < 2; p++) {
            int s2 = p * 256 + tid, e = s2 >> 4, c16 = s2 & 15;
            *(uint4*)(el + (size_t)(base + e) * 128 + c16 * 8) =
                *(const uint4*)(hid_s + e * 264 + c16 * 8);
        }
    }
}

// ---------------- MFMA edge processor step (CSR order; bf16 hi gather + snd-prefetch pipeline) ----------------

__global__ __launch_bounds__(256) void k_edge_step(
    unsigned short* __restrict__ el, const unsigned short* __restrict__ nlh,
    const unsigned short* __restrict__ snd, const unsigned short* __restrict__ rcv,
    const unsigned short* __restrict__ w1f, const float* __restrict__ b1,
    const unsigned short* __restrict__ w2f, const float* __restrict__ b2) {
    __shared__ __align__(16) unsigned short inl_s[32 * 392];
    __shared__ __align__(16) unsigned short hid_s[32 * 136];
    const int tid = threadIdx.x;
    const int wave = tid >> 6, lane = tid & 63;
    const int col = lane & 15, quad = lane >> 4;
    const int erow = tid >> 4, c16 = tid & 15;

    bf8v W1[12][2], W2[4][2];
#pragma unroll
    for (int kt = 0; kt < 12; kt++)
#pragma unroll
        for (int t = 0; t < 2; t++)
            W1[kt][t] = *(const bf8v*)(w1f + ((size_t)(kt * 8 + 2 * wave + t) * 64 + lane) * 8);
#pragma unroll
    for (int kt = 0; kt < 4; kt++)
#pragma unroll
        for (int t = 0; t < 2; t++)
            W2[kt][t] = *(const bf8v*)(w2f + ((size_t)(kt * 8 + 2 * wave + t) * 64 + lane) * 8);
    float bias1[2], bias2[2];
#pragma unroll
    for (int t = 0; t < 2; t++) {
        bias1[t] = b1[(2 * wave + t) * 16 + col];
        bias2[t] = b2[(2 * wave + t) * 16 + col];
    }

    // prologue: prefetch snd-side gathers for tile 0
    uint4 pf_s[2];
#pragma unroll
    for (int p = 0; p < 2; p++) {
        int ge = blockIdx.x * 128 + p * 16 + erow;
        pf_s[p] = *(const uint4*)(nlh + (size_t)snd[ge] * 128 + c16 * 8);
    }

    for (int it = 0; it < 4; it++) {
        const int base = blockIdx.x * 128 + it * 32;
        __syncthreads();  // prev-iter store-phase reads of LDS done
#pragma unroll
        for (int p = 0; p < 2; p++) {
            int e = p * 16 + erow;
            int ge = base + e;
            *(uint4*)(inl_s + e * 392 + c16 * 8) =
                *(const uint4*)(el + (size_t)ge * 128 + c16 * 8);
            *(uint4*)(inl_s + e * 392 + 128 + c16 * 8) = pf_s[p];
            *(uint4*)(inl_s + e * 392 + 256 + c16 * 8) =
                *(const uint4*)(nlh + (size_t)rcv[ge] * 128 + c16 * 8);
        }
        if (it < 3) {  // prefetch snd gathers for next tile (in flight across MFMA phases)
#pragma unroll
            for (int p = 0; p < 2; p++) {
                int ge = base + 32 + p * 16 + erow;
                pf_s[p] = *(const uint4*)(nlh + (size_t)snd[ge] * 128 + c16 * 8);
            }
        }
        __syncthreads();  // stage visible

        f4v acc[2][2];
#pragma unroll
        for (int mt = 0; mt < 2; mt++)
#pragma unroll
            for (int t = 0; t < 2; t++) acc[mt][t] = (f4v){0.f, 0.f, 0.f, 0.f};
#pragma unroll
        for (int kt = 0; kt < 12; kt++) {
            bf8v a0 = *(const bf8v*)(inl_s + col * 392 + kt * 32 + quad * 8);
            bf8v a1 = *(const bf8v*)(inl_s + (16 + col) * 392 + kt * 32 + quad * 8);
            acc[0][0] = __builtin_amdgcn_mfma_f32_16x16x32_bf16(a0, W1[kt][0], acc[0][0], 0, 0, 0);
            acc[0][1] = __builtin_amdgcn_mfma_f32_16x16x32_bf16(a0, W1[kt][1], acc[0][1], 0, 0, 0);
            acc[1][0] = __builtin_amdgcn_mfma_f32_16x16x32_bf16(a1, W1[kt][0], acc[1][0], 0, 0, 0);
            acc[1][1] = __builtin_amdgcn_mfma_f32_16x16x32_bf16(a1, W1[kt][1], acc[1][1], 0, 0, 0);
        }
#pragma unroll
        for (int mt = 0; mt < 2; mt++)
#pragma unroll
            for (int t = 0; t < 2; t++) {
                const int nc = (2 * wave + t) * 16 + col;
#pragma unroll
                for (int r = 0; r < 4; r++) {
                    float v = fmaxf(acc[mt][t][r] + bias1[t], 0.f);
                    hid_s[(mt * 16 + quad * 4 + r) * 136 + nc] = f2bf(v);
                }
            }
        __syncthreads();

#pragma unroll
        for (int mt = 0; mt < 2; mt++)
#pragma unroll
            for (int t = 0; t < 2; t++) acc[mt][t] = (f4v){0.f, 0.f, 0.f, 0.f};
#pragma unroll
        for (int kt = 0; kt < 4; kt++) {
            bf8v a0 = *(const bf8v*)(hid_s + col * 136 + kt * 32 + quad * 8);
            bf8v a1 = *(const bf8v*)(hid_s + (16 + col) * 136 + kt * 32 + quad * 8);
            acc[0][0] = __builtin_amdgcn_mfma_f32_16x16x32_bf16(a0, W2[kt][0], acc[0][0], 0, 0, 0);
            acc[0][1] = __builtin_amdgcn_mfma_f32_16x16x32_bf16(a0, W2[kt][1], acc[0][1], 0, 0, 0);
            acc[1][0] = __builtin_amdgcn_mfma_f32_16x16x32_bf16(a1, W2[kt][0], acc[1][0], 0, 0, 0);
            acc[1][1] = __builtin_amdgcn_mfma_f32_16x16x32_bf16(a1, W2[kt][1], acc[1][1], 0, 0, 0);
        }
        __syncthreads();  // all L2 reads of hid done
#pragma unroll
        for (int mt = 0; mt < 2; mt++)
#pragma unroll
            for (int t = 0; t < 2; t++) {
                const int nc = (2 * wave + t) * 16 + col;
#pragma unroll
                for (int r = 0; r < 4; r++) {
                    const int row = mt * 16 + quad * 4 + r;
                    float v = acc[mt][t][r] + bias2[t] + bflo((unsigned int)inl_s[row * 392 + nc]);
                    hid_s[row * 136 + nc] = f2bf(v);
                }
            }
        __syncthreads();  // out staged
#pragma unroll
        for (int p = 0; p < 2; p++) {
            int e = p * 16 + erow;
            *(uint4*)(el + (size_t)(base + e) * 128 + c16 * 8) =
                *(const uint4*)(hid_s + e * 136 + c16 * 8);
        }
    }
}

// ---------------- node step: [nl_hi|nl_lo|agg_hi] (K=384) -> 128 -> 128, residual, hi/lo out ----------------
// 64 nodes/block (2 tiles of 32), grid 782. agg precomputed bf16 by k_agg.

__global__ __launch_bounds__(256) void k_node_step_s(
    unsigned short* __restrict__ nlh, unsigned short* __restrict__ nll,
    const unsigned short* __restrict__ agg,
    const unsigned short* __restrict__ w1h, const unsigned short* __restrict__ w1l,
    const float* __restrict__ b1,
    const unsigned short* __restrict__ w2h, const unsigned short* __restrict__ w2l,
    const float* __restrict__ b2) {
    __shared__ __align__(16) unsigned short a_s[32 * 392];
    __shared__ __align__(16) unsigned short hid_s[32 * 264];
    const int tid = threadIdx.x, wave = tid >> 6, lane = tid & 63;
    const int col = lane & 15, quad = lane >> 4;
    bf8v W1H[8][2], W1L[8][2], W2H[4][2], W2L[4][2];
#pragma unroll
    for (int kt = 0; kt < 8; kt++)
#pragma unroll
        for (int t = 0; t < 2; t++) {
            W1H[kt][t] = *(const bf8v*)(w1h + ((size_t)(kt * 8 + 2 * wave + t) * 64 + lane) * 8);
            W1L[kt][t] = *(const bf8v*)(w1l + ((size_t)(kt * 8 + 2 * wave + t) * 64 + lane) * 8);
        }
#pragma unroll
    for (int kt = 0; kt < 4; kt++)
#pragma unroll
        for (int t = 0; t < 2; t++) {
            W2H[kt][t] = *(const bf8v*)(w2h + ((size_t)(kt * 8 + 2 * wave + t) * 64 + lane) * 8);
            W2L[kt][t] = *(const bf8v*)(w2l + ((size_t)(kt * 8 + 2 * wave + t) * 64 + lane) * 8);
        }
    float bias1[2], bias2[2];
#pragma unroll
    for (int t = 0; t < 2; t++) {
        bias1[t] = b1[(2 * wave + t) * 16 + col];
        bias2[t] = b2[(2 * wave + t) * 16 + col];
    }
    for (int it = 0; it < 2; it++) {
        const int base = blockIdx.x * 64 + it * 32;
        if (base >= NN) break;
        __syncthreads();  // prev-iter a_s/hid_s reads done
        // stage: direct uint4 copies (hi | lo | agg)
#pragma unroll
        for (int p = 0; p < 2; p++) {
            int e = p * 16 + (tid >> 4), c16 = tid & 15;
            int n = base + e; if (n > NN - 1) n = NN - 1;
            *(uint4*)(a_s + e * 392 + c16 * 8) =
                *(const uint4*)(nlh + (size_t)n * 128 + c16 * 8);
            *(uint4*)(a_s + e * 392 + 128 + c16 * 8) =
                *(const uint4*)(nll + (size_t)n * 128 + c16 * 8);
            *(uint4*)(a_s + e * 392 + 256 + c16 * 8) =
                *(const uint4*)(agg + (size_t)n * 128 + c16 * 8);
        }
        __syncthreads();

        f4v acc[2][2];
#pragma unroll
        for (int mt = 0; mt < 2; mt++)
#pragma unroll
            for (int t = 0; t < 2; t++) acc[mt][t] = (f4v){0.f, 0.f, 0.f, 0.f};
        // layer1: nl hi+lo vs W1H[0..3], agg vs W1H[4..7], nl hi vs W1L[0..3], agg vs W1L[4..7]
#pragma unroll
        for (int kt = 0; kt < 8; kt++) {
            bf8v a0 = *(const bf8v*)(a_s + col * 392 + kt * 32 + quad * 8);
            bf8v a1 = *(const bf8v*)(a_s + (16 + col) * 392 + kt * 32 + quad * 8);
#pragma unroll
            for (int t = 0; t < 2; t++) {
                acc[0][t] = __builtin_amdgcn_mfma_f32_16x16x32_bf16(a0, W1H[kt & 3][t], acc[0][t], 0, 0, 0);
                acc[1][t] = __builtin_amdgcn_mfma_f32_16x16x32_bf16(a1, W1H[kt & 3][t], acc[1][t], 0, 0, 0);
            }
        }
#pragma unroll
        for (int kt = 0; kt < 4; kt++) {
            bf8v a0 = *(const bf8v*)(a_s + col * 392 + 256 + kt * 32 + quad * 8);
            bf8v a1 = *(const bf8v*)(a_s + (16 + col) * 392 + 256 + kt * 32 + quad * 8);
#pragma unroll
            for (int t = 0; t < 2; t++) {
                acc[0][t] = __builtin_amdgcn_mfma_f32_16x16x32_bf16(a0, W1H[4 + kt][t], acc[0][t], 0, 0, 0);
                acc[1][t] = __builtin_amdgcn_mfma_f32_16x16x32_bf16(a1, W1H[4 + kt][t], acc[1][t], 0, 0, 0);
            }
        }
#pragma unroll
        for (int kt = 0; kt < 4; kt++) {
            bf8v a0 = *(const bf8v*)(a_s + col * 392 + kt * 32 + quad * 8);
            bf8v a1 = *(const bf8v*)(a_s + (16 + col) * 392 + kt * 32 + quad * 8);
#pragma unroll
            for (int t = 0; t < 2; t++) {
                acc[0][t] = __builtin_amdgcn_mfma_f32_16x16x32_bf16(a0, W1L[kt][t], acc[0][t], 0, 0, 0);
                acc[1][t] = __builtin_amdgcn_mfma_f32_16x16x32_bf16(a1, W1L[kt][t], acc[1][t], 0, 0, 0);
            }
        }
#pragma unroll
        for (int kt = 0; kt < 4; kt++) {
            bf8v a0 = *(const bf8v*)(a_s + col * 392 + 256 + kt * 32 + quad * 8);
            bf8v a1 = *(const bf8v*)(a_s + (16 + col) * 392 + 256 + kt * 32 + quad * 8);
#pragma unroll
            for (int t = 0; t < 2; t++) {
                acc[0][t] = __builtin_amdgcn_mfma_f32_16x16x32_bf16(a0, W1L[4 + kt][t], acc[0][t], 0, 0, 0);
                acc[1][t] = __builtin_amdgcn_mfma_f32_16x16x32_bf16(a1, W1L[4 + kt][t], acc[1][t], 0, 0, 0);
            }
        }
#pragma unroll
        for (int mt = 0; mt < 2; mt++)
#pragma unroll
            for (int t = 0; t < 2; t++) {
                const int nc = (2 * wave + t) * 16 + col;
#pragma unroll
                for (int r = 0; r < 4; r++) {
                    float h = fmaxf(acc[mt][t][r] + bias1[t], 0.f);
                    unsigned short hh = f2bf(h);
                    hid_s[(mt * 16 + quad * 4 + r) * 264 + nc] = hh;
                    hid_s[(mt * 16 + quad * 4 + r) * 264 + 128 + nc] = f2bf(h - bflo(hh));
                }
            }
        __syncthreads();
#pragma unroll
        for (int mt = 0; mt < 2; mt++)
#pragma unroll
            for (int t = 0; t < 2; t++) acc[mt][t] = (f4v){0.f, 0.f, 0.f, 0.f};
#pragma unroll
        for (int kt = 0; kt < 8; kt++) {
            int w = kt & 3;
            bf8v a0 = *(const bf8v*)(hid_s + col * 264 + kt * 32 + quad * 8);
            bf8v a1 = *(const bf8v*)(hid_s + (16 + col) * 264 + kt * 32 + quad * 8);
#pragma unroll
            for (int t = 0; t < 2; t++) {
                acc[0][t] = __builtin_amdgcn_mfma_f32_16x16x32_bf16(a0, W2H[w][t], acc[0][t], 0, 0, 0);
                acc[1][t] = __builtin_amdgcn_mfma_f32_16x16x32_bf16(a1, W2H[w][t], acc[1][t], 0, 0, 0);
            }
        }
#pragma unroll
        for (int kt = 0; kt < 4; kt++) {
            bf8v a0 = *(const bf8v*)(hid_s + col * 264 + kt * 32 + quad * 8);
            bf8v a1 = *(const bf8v*)(hid_s + (16 + col) * 264 + kt * 32 + quad * 8);
#pragma unroll
            for (int t = 0; t < 2; t++) {
                acc[0][t] = __builtin_amdgcn_mfma_f32_16x16x32_bf16(a0, W2L[kt][t], acc[0][t], 0, 0, 0);
                acc[1][t] = __builtin_amdgcn_mfma_f32_16x16x32_bf16(a1, W2L[kt][t], acc[1][t], 0, 0, 0);
            }
        }
        __syncthreads();  // all L2 reads of hid done; reuse hid_s for output staging
#pragma unroll
        for (int mt = 0; mt < 2; mt++)
#pragma unroll
            for (int t = 0; t < 2; t++) {
                const int nc = (2 * wave + t) * 16 + col;
#pragma unroll
                for (int r = 0; r < 4; r++) {
                    const int row = mt * 16 + quad * 4 + r;
                    // residual from a_s hi+lo (still intact)
                    float res = bflo((unsigned int)a_s[row * 392 + nc]) +
                                bflo((unsigned int)a_s[row * 392 + 128 + nc]);
                    float v = acc[mt][t][r] + bias2[t] + res;
                    unsigned short hh = f2bf(v);
                    hid_s[row * 264 + nc] = hh;
                    hid_s[row * 264 + 128 + nc] = f2bf(v - bflo(hh));
                }
            }
        __syncthreads();  // out staged
#pragma unroll
        for (int p = 0; p < 2; p++) {
            int e = p * 16 + (tid >> 4), c16 = tid & 15;
            if (base + e < NN) {
                *(uint4*)(nlh + (size_t)(base + e) * 128 + c16 * 8) =
                    *(const uint4*)(hid_s + e * 264 + c16 * 8);
                *(uint4*)(nll + (size_t)(base + e) * 128 + c16 * 8) =
                    *(const uint4*)(hid_s + e * 264 + 128 + c16 * 8);
            }
        }
    }
}

// ---------------- decoder: 128 -> 128 -> 3 (fp32 VALU, reads hi+lo) ----------------

__global__ __launch_bounds__(128) void k_decode(
    const unsigned short* __restrict__ nlh, const unsigned short* __restrict__ nll,
    const float* __restrict__ w1, const float* __restrict__ b1,
    const float* __restrict__ w2, const float* __restrict__ b2,
    float* __restrict__ out) {
    __shared__ float inl[16][128];
    __shared__ float hid[16][128];
    int j = threadIdx.x;
    int base = blockIdx.x * 16;
    for (int e = 0; e < 16; e++)
        inl[e][j] = bflo((unsigned int)nlh[(size_t)(base + e) * 128 + j]) +
                    bflo((unsigned int)nll[(size_t)(base + e) * 128 + j]);
    __syncthreads();
    float acc[16];
#pragma unroll
    for (int e = 0; e < 16; e++) acc[e] = b1[j];
    for (int kc = 0; kc < 16; kc++) {
        float w[8];
#pragma unroll
        for (int t = 0; t < 8; t++) w[t] = w1[(kc * 8 + t) * 128 + j];
#pragma unroll
        for (int e = 0; e < 16; e++) {
            float4 h0 = *(const float4*)&inl[e][kc * 8];
            float4 h1 = *(const float4*)&inl[e][kc * 8 + 4];
            acc[e] = fmaf(h0.x, w[0], acc[e]); acc[e] = fmaf(h0.y, w[1], acc[e]);
            acc[e] = fmaf(h0.z, w[2], acc[e]); acc[e] = fmaf(h0.w, w[3], acc[e]);
            acc[e] = fmaf(h1.x, w[4], acc[e]); acc[e] = fmaf(h1.y, w[5], acc[e]);
            acc[e] = fmaf(h1.z, w[6], acc[e]); acc[e] = fmaf(h1.w, w[7], acc[e]);
        }
    }
#pragma unroll
    for (int e = 0; e < 16; e++) hid[e][j] = fmaxf(acc[e], 0.f);
    __syncthreads();
    if (j < 48) {
        int e = j / 3, ch = j - 3 * (j / 3);
        float s = b2[ch];
        for (int k = 0; k < 128; k++) s = fmaf(hid[e][k], w2[k * 3 + ch], s);
        out[(size_t)(base + e) * 3 + ch] = s;
    }
}

// ---------------- launch ----------------

extern "C" void kernel_launch(void* const* d_in, const int* in_sizes, int n_in,
                              void* d_out, int out_size, void* d_ws, size_t ws_size,
                              hipStream_t stream) {
    (void)in_sizes; (void)n_in; (void)out_size; (void)ws_size;
    const float* pos   = (const float*)d_in[0];
    const float* vel   = (const float*)d_in[1];
    const int*   rid   = (const int*)d_in[2];
    const int*   snd   = (const int*)d_in[3];
    const int*   rcv   = (const int*)d_in[4];
    const float* remb  = (const float*)d_in[5];
    const float* ne_w1 = (const float*)d_in[6];
    const float* ne_b1 = (const float*)d_in[7];
    const float* ne_w2 = (const float*)d_in[8];
    const float* ne_b2 = (const float*)d_in[9];
    const float* ee_w1 = (const float*)d_in[10];
    const float* ee_b1 = (const float*)d_in[11];
    const float* ee_w2 = (const float*)d_in[12];
    const float* ee_b2 = (const float*)d_in[13];
    const float* pe_w1 = (const float*)d_in[14];
    const float* pe_b1 = (const float*)d_in[15];
    const float* pe_w2 = (const float*)d_in[16];
    const float* pe_b2 = (const float*)d_in[17];
    const float* pn_w1 = (const float*)d_in[18];
    const float* pn_b1 = (const float*)d_in[19];
    const float* pn_w2 = (const float*)d_in[20];
    const float* pn_b2 = (const float*)d_in[21];
    const float* de_w1 = (const float*)d_in[22];
    const float* de_b1 = (const float*)d_in[23];
    const float* de_w2 = (const float*)d_in[24];
    const float* de_b2 = (const float*)d_in[25];
    float* out = (float*)d_out;

    // workspace carve (~250.6e6 B — under the 256.2e6 proven available)
    char* p = (char*)d_ws;
    auto carve = [&](size_t bytes) { void* q = (void*)p; p += (bytes + 15) & ~(size_t)15; return q; };
    unsigned short* el    = (unsigned short*)carve((size_t)NE * LDIM * 2);   // 204.8e6, CSR order
    unsigned short* nlh   = (unsigned short*)carve((size_t)NN * LDIM * 2);   // 12.8e6
    unsigned short* nll   = (unsigned short*)carve((size_t)NN * LDIM * 2);   // 12.8e6
    unsigned short* agg   = (unsigned short*)carve((size_t)NN * LDIM * 2);   // 12.8e6 (bf16)
    unsigned short* w1f_e = (unsigned short*)carve((size_t)NSTEPS * 12 * 8 * 512 * 2);
    unsigned short* w2f_e = (unsigned short*)carve((size_t)NSTEPS * 4 * 8 * 512 * 2);
    unsigned short* w1h_n = (unsigned short*)carve((size_t)NSTEPS * 8 * 8 * 512 * 2);
    unsigned short* w1l_n = (unsigned short*)carve((size_t)NSTEPS * 8 * 8 * 512 * 2);
    unsigned short* w2h_n = (unsigned short*)carve((size_t)NSTEPS * 4 * 8 * 512 * 2);
    unsigned short* w2l_n = (unsigned short*)carve((size_t)NSTEPS * 4 * 8 * 512 * 2);
    unsigned short* eew1h = (unsigned short*)carve((size_t)1 * 8 * 512 * 2);
    unsigned short* eew1l = (unsigned short*)carve((size_t)1 * 8 * 512 * 2);
    unsigned short* eew2h = (unsigned short*)carve((size_t)4 * 8 * 512 * 2);
    unsigned short* eew2l = (unsigned short*)carve((size_t)4 * 8 * 512 * 2);
    unsigned short* new1h = (unsigned short*)carve((size_t)1 * 8 * 512 * 2);
    unsigned short* new1l = (unsigned short*)carve((size_t)1 * 8 * 512 * 2);
    unsigned short* new2h = (unsigned short*)carve((size_t)4 * 8 * 512 * 2);
    unsigned short* new2l = (unsigned short*)carve((size_t)4 * 8 * 512 * 2);
    unsigned short* snd_p = (unsigned short*)carve((size_t)NE * 2);          // 1.6e6
    unsigned short* rcv_p = (unsigned short*)carve((size_t)NE * 2);          // 1.6e6
    int*            rs    = (int*)carve((size_t)(NN + 1) * 4);
    int*            cnt   = (int*)carve((size_t)NN * 4);
    int*            cur   = (int*)carve((size_t)NN * 4);
    float*          degf  = (float*)carve((size_t)NN * 4);
    float*          csum  = (float*)carve(16);

    hipMemsetAsync(cnt, 0, (size_t)NN * 4, stream);
    hipMemsetAsync(csum, 0, 16, stream);
    k_hist<<<NE / 256, 256, 0, stream>>>(rcv, cnt);
    k_scan<<<1, 1024, 0, stream>>>(cnt, rs, cur, degf);
    k_center<<<64, 256, 0, stream>>>(pos, csum);
    k_scatter<<<NE / 256, 256, 0, stream>>>(snd, rcv, cur, snd_p, rcv_p);
    k_prep_w<<<NSTEPS * 12 * 8, 64, 0, stream>>>(pe_w1, w1f_e, 12, 384, 0);
    k_prep_w<<<NSTEPS * 4 * 8, 64, 0, stream>>>(pe_w2, w2f_e, 4, 128, 0);
    k_prep_w<<<NSTEPS * 8 * 8, 64, 0, stream>>>(pn_w1, w1h_n, 8, 256, 0);
    k_prep_w<<<NSTEPS * 8 * 8, 64, 0, stream>>>(pn_w1, w1l_n, 8, 256, 1);
    k_prep_w<<<NSTEPS * 4 * 8, 64, 0, stream>>>(pn_w2, w2h_n, 4, 128, 0);
    k_prep_w<<<NSTEPS * 4 * 8, 64, 0, stream>>>(pn_w2, w2l_n, 4, 128, 1);
    k_prep_w<<<8, 64, 0, stream>>>(ee_w1, eew1h, 1, 9, 0);
    k_prep_w<<<8, 64, 0, stream>>>(ee_w1, eew1l, 1, 9, 1);
    k_prep_w<<<4 * 8, 64, 0, stream>>>(ee_w2, eew2h, 4, 128, 0);
    k_prep_w<<<4 * 8, 64, 0, stream>>>(ee_w2, eew2l, 4, 128, 1);
    k_prep_w<<<8, 64, 0, stream>>>(ne_w1, new1h, 1, 23, 0);
    k_prep_w<<<8, 64, 0, stream>>>(ne_w1, new1l, 1, 23, 1);
    k_prep_w<<<4 * 8, 64, 0, stream>>>(ne_w2, new2h, 4, 128, 0);
    k_prep_w<<<4 * 8, 64, 0, stream>>>(ne_w2, new2l, 4, 128, 1);

    k_node_enc_m<<<(NN + 127) / 128, 256, 0, stream>>>(pos, vel, rid, remb, degf, csum,
                                                       new1h, new1l, ne_b1, new2h, new2l, ne_b2, nlh, nll);
    k_edge_enc_m<<<NE / 128, 256, 0, stream>>>(pos, vel, rid, snd_p, rcv_p,
                                               eew1h, eew1l, ee_b1, eew2h, eew2l, ee_b2, el);
    for (int i = 0; i < NSTEPS; i++) {
        k_edge_step<<<NE / 128, 256, 0, stream>>>(el, nlh, snd_p, rcv_p,
            w1f_e + (size_t)i * 12 * 8 * 512, pe_b1 + i * 128,
            w2f_e + (size_t)i * 4 * 8 * 512, pe_b2 + i * 128);
        k_agg<<<(NN + 3) / 4, 256, 0, stream>>>(el, rs, agg);
        k_node_step_s<<<(NN + 63) / 64, 256, 0, stream>>>(nlh, nll, agg,
            w1h_n + (size_t)i * 8 * 8 * 512, w1l_n + (size_t)i * 8 * 8 * 512, pn_b1 + i * 128,
            w2h_n + (size_t)i * 4 * 8 * 512, w2l_n + (size_t)i * 4 * 8 * 512, pn_b2 + i * 128);
    }
    k_decode<<<NN / 16, 128, 0, stream>>>(nlh, nll, de_w1, de_b1, de_w2, de_b2, out);
}